// Round 8
// baseline (439.498 us; speedup 1.0000x reference)
//
#include <hip/hip_runtime.h>
#include <cstdint>
#include <cstddef>

// ---------------- types / helpers ----------------
typedef __attribute__((ext_vector_type(8))) __bf16 bf16x8;
typedef __attribute__((ext_vector_type(4))) float f32x4;
typedef __attribute__((ext_vector_type(16))) float f32x16;

__device__ __forceinline__ unsigned short f2b(float x) {
    uint32_t u = __float_as_uint(x);
    u += 0x7FFFu + ((u >> 16) & 1u);   // RNE
    return (unsigned short)(u >> 16);
}
__device__ __forceinline__ float b2f(unsigned short h) {
    return __uint_as_float(((uint32_t)h) << 16);
}

// async global->LDS, 16B per lane. LDS dest is wave-uniform base (+lane*16 by HW).
__device__ __forceinline__ void gl16(const unsigned short* g, unsigned short* l) {
    __builtin_amdgcn_global_load_lds((const __attribute__((address_space(1))) uint32_t*)g,
                                     (__attribute__((address_space(3))) uint32_t*)l, 16, 0, 0);
}

#define L_SEQ 512
#define N_AA 21
#define DDIM 128
#define NCOL 2688        // 21*128
#define NSEQ 512         // 256 + 256
#define TBSTRIDE 448     // Tb row stride (u16), 441 used
#define KTOT 10752       // 512*21
#define ZCH 12           // k-chunks (partial-slab count)
#define KBTOT 672        // 10752/16 k-subtiles
#define KBCH 56          // 672/12 k-subtiles per chunk

// block-range sizes inside prep_kernel
#define PB_WBZ   2688    // 672 kb x 4 col-windows (LDS transpose-staged)
#define PB_REPACK 1024
#define PB_WBUILD 1024
#define PB_ABZ   2688    // 16*672/4 fragments
#define PB_TOTAL (PB_WBZ + PB_REPACK + PB_WBUILD + PB_ABZ)

#define WS_PAD 684       // LDS row stride (u16) for the W tile
#define SH_PAD 516       // Sh row stride (u16): 258 dwords == 2 mod 32 -> 2-way (free) on b128

// ---------------- kernel 1: fused prologue ----------------
__global__ __launch_bounds__(256) void prep_kernel(const int* X1, const int* X2,
                                                   const float* W, const float* wp,
                                                   uint8_t* X8,
                                                   float* w32, unsigned short* wswz,
                                                   unsigned short* Wbz, unsigned short* Abz) {
    __shared__ unsigned short Ws[16 * WS_PAD];   // 21.9 KB, only used by the Wbz job
    int bid = blockIdx.x;
    int t = threadIdx.x;
    if (bid < PB_WBZ) {
        int kb = bid >> 2, cw = bid & 3;         // 16 rows starting r0, 672-col window c0
        int r0 = kb * 16, c0 = cw * 672;
        // phase 1: contiguous W read (float4/lane), bf16-convert into LDS tile [16][WS_PAD]
        for (int e = t; e < 16 * 168; e += 256) {
            int ri = e / 168, c4 = e - ri * 168;
            float4 v = *(const float4*)(W + (size_t)(r0 + ri) * NCOL + c0 + c4 * 4);
            union { ushort4 q; unsigned short s[4]; } o;
            o.s[0] = f2b(v.x); o.s[1] = f2b(v.y); o.s[2] = f2b(v.z); o.s[3] = f2b(v.w);
            *(ushort4*)&Ws[ri * WS_PAD + c4 * 4] = o.q;
        }
        __syncthreads();
        // phase 2: gather fragment order from LDS, contiguous Wbz write (uint4/lane)
        for (int e = t; e < 21 * 64; e += 256) {
            int fi = e >> 6, sl = e & 63;
            int lr = sl & 31, hf = sl >> 5;
            union { uint4 q; unsigned short s[8]; } o;
#pragma unroll
            for (int j = 0; j < 8; ++j) o.s[j] = Ws[(hf * 8 + j) * WS_PAD + fi * 32 + lr];
            int cb = cw * 21 + fi;
            *(uint4*)&Wbz[((size_t)cb * KBTOT + kb) * 512 + sl * 8] = o.q;
        }
        return;
    }
    bid -= PB_WBZ;
    if (bid < PB_REPACK) {
        int e = bid * 256 + t;             // 262,144
        if (e < 131072) X8[e] = (uint8_t)X1[e];
        else            X8[e] = (uint8_t)X2[e - 131072];
        return;
    }
    bid -= PB_REPACK;
    if (bid < PB_WBUILD) {
        int e = bid * 256 + t;             // 262,144 = 512*512
        int p = e >> 9, q = e & 511;
        float x = 0.0f;
        if (p > q)      x = wp[p * (p - 1) / 2 + q];
        else if (p < q) x = wp[q * (q - 1) / 2 + p];
        float s = 1.0f / (1.0f + expf(-x));
        w32[e] = s;
        int nb = p >> 5, lr = p & 31;
        int kb = q >> 4, hf = (q >> 3) & 1, j = q & 7;
        wswz[(size_t)((nb * 32 + kb) * 512) + (hf * 32 + lr) * 8 + j] = f2b(s);
        return;
    }
    bid -= PB_WBUILD;
    {
        // Abz fragment (mb,kb): lane (hf,lr) holds onehot(X[mb*32+lr], k=kb*16+hf*8+j)
        int f = bid * 4 + (t >> 6);        // 0..10751
        int lane = t & 63, lr = lane & 31, hf = lane >> 5;
        int mb = f / KBTOT, kb = f - mb * KBTOT;
        int m = mb * 32 + lr;
        const int* Xrow = (m < 256) ? (X1 + (size_t)m * L_SEQ) : (X2 + (size_t)(m - 256) * L_SEQ);
        int k0 = kb * 16 + hf * 8;
        union { uint4 q; unsigned short s[8]; } o;
#pragma unroll
        for (int j = 0; j < 8; ++j) {
            int k = k0 + j;
            int l = k / N_AA;
            int aa = k - l * N_AA;
            o.s[j] = (Xrow[l] == aa) ? (unsigned short)0x3F80u : (unsigned short)0u;
        }
        *(uint4*)&Abz[(size_t)f * 512 + lane * 8] = o.q;
    }
}

// ---------------- kernel 2: Ep[kz] = A @ W — LDS ring, single barrier per K-step ------
__global__ __launch_bounds__(256, 4) void e_mfma_v6(const unsigned short* Abz, const unsigned short* Wbz, float* Ep) {
    __shared__ unsigned short lds[4 * 8 * 512];   // 4 bufs x 8 frags x 1024 B = 32 KB

    int lin = blockIdx.x;
    int s = ((lin & 7) * 126) + (lin >> 3);    // bijective XCD swizzle (1008 % 8 == 0)
    int cx = s % 21;
    int rem = s / 21;                           // 0..47
    int my = rem & 3;
    int kz = rem >> 2;                          // 0..11

    int t = threadIdx.x, wid = t >> 6, lane = t & 63;
    int lr = lane & 31, hf = lane >> 5;
    int kb0 = kz * KBCH;

    const unsigned short* Aw = Abz + ((size_t)((my * 4 + wid) * KBTOT + kb0)) * 512 + lane * 8;
    const unsigned short* Bw = Wbz + ((size_t)((cx * 4 + wid) * KBTOT + kb0)) * 512 + lane * 8;
    unsigned short* La = &lds[wid * 512];
    unsigned short* Lb = &lds[(4 + wid) * 512];

#define STG(buf_, kb_) do { \
        gl16(Aw + (size_t)(kb_) * 512, La + (buf_) * 4096); \
        gl16(Bw + (size_t)(kb_) * 512, Lb + (buf_) * 4096); \
    } while (0)

    int alo = (wid & 1) * 2;          // A frag slots this wave consumes
    int blo = 4 + (wid >> 1) * 2;     // B frag slots

    f32x16 acc00, acc01, acc10, acc11;
#pragma unroll
    for (int r = 0; r < 16; ++r) { acc00[r] = 0.f; acc01[r] = 0.f; acc10[r] = 0.f; acc11[r] = 0.f; }

#define COMPUTE(kb_) do { \
        const unsigned short* base = &lds[((kb_) & 3) * 4096]; \
        bf16x8 a0 = *(const bf16x8*)(base + (alo + 0) * 512 + lane * 8); \
        bf16x8 a1 = *(const bf16x8*)(base + (alo + 1) * 512 + lane * 8); \
        bf16x8 b0 = *(const bf16x8*)(base + (blo + 0) * 512 + lane * 8); \
        bf16x8 b1 = *(const bf16x8*)(base + (blo + 1) * 512 + lane * 8); \
        acc00 = __builtin_amdgcn_mfma_f32_32x32x16_bf16(a0, b0, acc00, 0, 0, 0); \
        acc01 = __builtin_amdgcn_mfma_f32_32x32x16_bf16(a0, b1, acc01, 0, 0, 0); \
        acc10 = __builtin_amdgcn_mfma_f32_32x32x16_bf16(a1, b0, acc10, 0, 0, 0); \
        acc11 = __builtin_amdgcn_mfma_f32_32x32x16_bf16(a1, b1, acc11, 0, 0, 0); \
    } while (0)

    // prologue: stage kb=0,1,2 (6 loads/wave outstanding)
    STG(0, 0); STG(1, 1); STG(2, 2);

#pragma unroll 1
    for (int kb = 0; kb < KBCH - 3; ++kb) {
        asm volatile("s_waitcnt vmcnt(4)" ::: "memory"); // this wave's kb loads landed
        __builtin_amdgcn_s_barrier();                    // all waves' kb landed AND compute(kb-1) done
        __builtin_amdgcn_sched_barrier(0);
        STG((kb + 3) & 3, kb + 3);                       // overwrite buf[(kb-1)&3] — safe post-barrier
        COMPUTE(kb);
    }
    // tail
    asm volatile("s_waitcnt vmcnt(4)" ::: "memory");
    __builtin_amdgcn_s_barrier();
    __builtin_amdgcn_sched_barrier(0);
    COMPUTE(KBCH - 3);
    asm volatile("s_waitcnt vmcnt(2)" ::: "memory");
    __builtin_amdgcn_s_barrier();
    __builtin_amdgcn_sched_barrier(0);
    COMPUTE(KBCH - 2);
    asm volatile("s_waitcnt vmcnt(0)" ::: "memory");
    __builtin_amdgcn_s_barrier();
    __builtin_amdgcn_sched_barrier(0);
    COMPUTE(KBCH - 1);

#undef STG
#undef COMPUTE

    int mb0 = my * 4 + (wid & 1) * 2;        // m-fragment index (32-row units)
    int cb0 = cx * 4 + (wid >> 1) * 2;       // c-fragment index (32-col units)
    float* slab = Ep + (size_t)kz * NSEQ * NCOL;
#pragma unroll
    for (int r = 0; r < 16; ++r) {
        int row = (r & 3) + 8 * (r >> 2) + 4 * hf;
        float* base = slab + (size_t)(mb0 * 32 + row) * NCOL + cb0 * 32 + lr;
        base[0] = acc00[r];
        base[32] = acc01[r];
        base[(size_t)32 * NCOL] = acc10[r];
        base[(size_t)32 * NCOL + 32] = acc11[r];
    }
}

// ---------------- kernel 3: T[n] = E[n] @ E[n]^T, E[n] = sum_z Ep[z][n] + bias --------
__global__ __launch_bounds__(256) void t_kernel(const float* Ep, const float* bvec,
                                                unsigned short* Tb, float* Tdiag) {
    __shared__ float4 Es4[21 * 33];
    int t = threadIdx.x, n = blockIdx.x;
    for (int idx = t; idx < 672; idx += 256) {          // 672 float4 = 2688 cols
        const float4* bp = (const float4*)(bvec + idx * 4);
        float4 acc = *bp;
#pragma unroll
        for (int z = 0; z < ZCH; ++z) {
            float4 v = *(const float4*)(Ep + ((size_t)z * NSEQ + n) * NCOL + idx * 4);
            acc.x += v.x; acc.y += v.y; acc.z += v.z; acc.w += v.w;
        }
        int r = idx >> 5, d = idx & 31;
        Es4[r * 33 + d] = acc;
    }
    __syncthreads();
    for (int e = t; e < 441; e += 256) {
        int r = e / 21, c = e - r * 21;
        const float4* ar = &Es4[r * 33];
        const float4* br = &Es4[c * 33];
        float s = 0.f;
#pragma unroll 8
        for (int d = 0; d < 32; ++d) {
            float4 a = ar[d], b = br[d];
            s += a.x * b.x + a.y * b.y + a.z * b.z + a.w * b.w;
        }
        Tb[(size_t)n * TBSTRIDE + e] = f2b(0.5f * s);
        if (r == c) Tdiag[n * 24 + r] = s;
    }
}

// ---------------- kernel 4: kinv — coalesced wave-per-row bilinear form ----------------
__global__ __launch_bounds__(512) void k_kernel(const uint8_t* X8, const float* Tdiag, const float* w32, float* kinv) {
    __shared__ __align__(16) float dvec[4][512];
    __shared__ float Td[4][21];
    __shared__ float wred[4][8];
    int t = threadIdx.x, n0 = blockIdx.x * 4;
    if (t < 84) Td[t / 21][t % 21] = Tdiag[(size_t)(n0 + t / 21) * 24 + (t % 21)];
    __syncthreads();
    for (int e = t; e < 2048; e += 512) {
        int nn = e >> 9, l = e & 511;
        dvec[nn][l] = Td[nn][X8[(size_t)(n0 + nn) * 512 + l]];
    }
    __syncthreads();
    int wid = t >> 6, lane = t & 63;
    int q0 = lane * 8;

    float4 dA0 = *(const float4*)&dvec[0][q0], dA1 = *(const float4*)&dvec[0][q0 + 4];
    float4 dB0 = *(const float4*)&dvec[1][q0], dB1 = *(const float4*)&dvec[1][q0 + 4];
    float4 dC0 = *(const float4*)&dvec[2][q0], dC1 = *(const float4*)&dvec[2][q0 + 4];
    float4 dD0 = *(const float4*)&dvec[3][q0], dD1 = *(const float4*)&dvec[3][q0 + 4];

    float4 rA0 = {0,0,0,0}, rA1 = {0,0,0,0}, rB0 = {0,0,0,0}, rB1 = {0,0,0,0};
    float4 rC0 = {0,0,0,0}, rC1 = {0,0,0,0}, rD0 = {0,0,0,0}, rD1 = {0,0,0,0};

#define FMA4(R, W, S) do { (R).x += (W).x * (S); (R).y += (W).y * (S); (R).z += (W).z * (S); (R).w += (W).w * (S); } while (0)
    for (int p = wid; p < 512; p += 8) {
        const float4* wr = (const float4*)(w32 + (size_t)p * 512 + q0);
        float4 w0v = wr[0], w1v = wr[1];
        float a = dvec[0][p], b = dvec[1][p], c = dvec[2][p], d = dvec[3][p];
        FMA4(rA0, w0v, a); FMA4(rA1, w1v, a);
        FMA4(rB0, w0v, b); FMA4(rB1, w1v, b);
        FMA4(rC0, w0v, c); FMA4(rC1, w1v, c);
        FMA4(rD0, w0v, d); FMA4(rD1, w1v, d);
    }
#undef FMA4

#define DOT8(R0, R1, D0, D1) ((R0).x*(D0).x + (R0).y*(D0).y + (R0).z*(D0).z + (R0).w*(D0).w + \
                              (R1).x*(D1).x + (R1).y*(D1).y + (R1).z*(D1).z + (R1).w*(D1).w)
    float s0 = DOT8(rA0, rA1, dA0, dA1);
    float s1 = DOT8(rB0, rB1, dB0, dB1);
    float s2 = DOT8(rC0, rC1, dC0, dC1);
    float s3 = DOT8(rD0, rD1, dD0, dD1);
#undef DOT8

#pragma unroll
    for (int off = 1; off < 64; off <<= 1) {
        s0 += __shfl_xor(s0, off);
        s1 += __shfl_xor(s1, off);
        s2 += __shfl_xor(s2, off);
        s3 += __shfl_xor(s3, off);
    }
    if (lane == 0) { wred[0][wid] = s0; wred[1][wid] = s1; wred[2][wid] = s2; wred[3][wid] = s3; }
    __syncthreads();
    if (t < 4) {
        float kk = 0.f;
#pragma unroll
        for (int w = 0; w < 8; ++w) kk += wred[t][w];
        kinv[n0 + t] = 1.0f / sqrtf(kk);
    }
}

// ---------------- kernel 5: pair GEMM v3 — 64 pairs (4i x 16j), 16 waves, halved B-L2 --
// Round-7 counters: k4's pole was B (wswz) L2 traffic — every 32-pair block streamed the
// whole 512 KB table (1.0 GB total). 64 pairs/block halves it. Wave w owns col-frag w
// (32 q-cols) and both A row-frags (pairs 0-31, 32-63): per k-step 1 B load + 2 MFMA.
// Sh pad 516 (2-way/free on b128, was 4-way at 520). LDS ~100 KB (gfx950 limit 160 KB).
__global__ __launch_bounds__(1024, 4) void k4_kernel(const uint8_t* X8, const unsigned short* Tb,
                                                     const unsigned short* wswz, const float* kinv,
                                                     const float* Ainp, float* out) {
    __shared__ unsigned short Sh[64 * SH_PAD];        // 66,048 B
    __shared__ unsigned short Ts1h[4 * TBSTRIDE];     //  3,584
    __shared__ unsigned short Ts2h[16 * TBSTRIDE];    // 14,336
    __shared__ unsigned short A21[4 * 512];           //  4,096
    __shared__ uint8_t Xs2[16 * 512];                 //  8,192
    __shared__ float Kacc[16][64];                    //  4,096

    int t = threadIdx.x;
    int i0 = blockIdx.x * 4;
    int j0 = blockIdx.y * 16;

    for (int e = t; e < 4 * 512; e += 1024)
        A21[e] = (unsigned short)(21 * X8[(size_t)(i0 + (e >> 9)) * 512 + (e & 511)]);
    {
        const uint32_t* s2 = (const uint32_t*)(X8 + (size_t)(256 + j0) * 512);
        uint32_t* d2 = (uint32_t*)Xs2;
        for (int e = t; e < 2048; e += 1024) d2[e] = s2[e];
    }
    {
        // Tb rows are already 0.5*T in bf16 — straight u32 copies (448 u16 = 224 u32 per row)
        uint32_t* d1 = (uint32_t*)Ts1h;
        for (int e = t; e < 4 * 224; e += 1024) {
            int r = e / 224, w = e - r * 224;
            d1[e] = ((const uint32_t*)(Tb + (size_t)(i0 + r) * TBSTRIDE))[w];
        }
        uint32_t* d2 = (uint32_t*)Ts2h;
        for (int e = t; e < 16 * 224; e += 1024) {
            int r = e / 224, w = e - r * 224;
            d2[e] = ((const uint32_t*)(Tb + (size_t)(256 + j0 + r) * TBSTRIDE))[w];
        }
    }
    __syncthreads();

    // build S tile: 64 rows x 512, 4 elems per thread-iter, packed u64 write
    for (int e4 = t; e4 < 64 * 128; e4 += 1024) {
        int pr = e4 >> 7, p = (e4 & 127) * 4;
        int ti = pr >> 4, tj = pr & 15;
        uint64_t a4 = *(const uint64_t*)&A21[ti * 512 + p];   // 4 u16 (a*21)
        uint32_t b4 = *(const uint32_t*)&Xs2[tj * 512 + p];   // 4 u8
        const unsigned short* T1 = &Ts1h[ti * TBSTRIDE];
        const unsigned short* T2 = &Ts2h[tj * TBSTRIDE];
        uint64_t outw = 0;
#pragma unroll
        for (int u = 0; u < 4; ++u) {
            int idx = (int)((a4 >> (16 * u)) & 0xFFFFu) + (int)((b4 >> (8 * u)) & 0xFFu);
            float v = b2f(T1[idx]) + b2f(T2[idx]);
            outw |= (uint64_t)f2b(v) << (16 * u);
        }
        *(uint64_t*)&Sh[pr * SH_PAD + p] = outw;
    }
    __syncthreads();

    int wid = t >> 6, lane = t & 63;
    int lr = lane & 31, hf = lane >> 5;

    const unsigned short* Sa0 = &Sh[lr * SH_PAD + hf * 8];
    const unsigned short* Sa1 = Sa0 + 32 * SH_PAD;
    const unsigned short* Bz = wswz + (size_t)(wid * 32) * 512 + lane * 8;

    f32x16 acc0, acc1;
#pragma unroll
    for (int j = 0; j < 16; ++j) { acc0[j] = 0.f; acc1[j] = 0.f; }

#pragma unroll 2
    for (int kt = 0; kt < 32; ++kt) {
        bf16x8 bv  = *(const bf16x8*)(Bz + kt * 512);
        bf16x8 av0 = *(const bf16x8*)(Sa0 + kt * 16);
        bf16x8 av1 = *(const bf16x8*)(Sa1 + kt * 16);
        acc0 = __builtin_amdgcn_mfma_f32_32x32x16_bf16(av0, bv, acc0, 0, 0, 0);
        acc1 = __builtin_amdgcn_mfma_f32_32x32x16_bf16(av1, bv, acc1, 0, 0, 0);
    }

#pragma unroll
    for (int r = 0; r < 16; ++r) {
        int row = (r & 3) + 8 * (r >> 2) + 4 * hf;
        float v0 = acc0[r] * b2f(Sh[row * SH_PAD + wid * 32 + lr]);
        float v1 = acc1[r] * b2f(Sh[(row + 32) * SH_PAD + wid * 32 + lr]);
        v0 += __shfl_xor(v0, 1);  v1 += __shfl_xor(v1, 1);
        v0 += __shfl_xor(v0, 2);  v1 += __shfl_xor(v1, 2);
        v0 += __shfl_xor(v0, 4);  v1 += __shfl_xor(v1, 4);
        v0 += __shfl_xor(v0, 8);  v1 += __shfl_xor(v1, 8);
        v0 += __shfl_xor(v0, 16); v1 += __shfl_xor(v1, 16);
        if (lr == 0) {
            Kacc[wid][row] = v0;
            Kacc[wid][32 + row] = v1;
        }
    }
    __syncthreads();

    if (t < 64) {
        float K = 0.f;
#pragma unroll
        for (int w = 0; w < 16; ++w) K += Kacc[w][t];
        int ti = t >> 4, tj = t & 15;
        int i = i0 + ti, j = j0 + tj;
        float a0 = Ainp[0];
        out[i * 256 + j] = a0 * a0 * K * kinv[i] * kinv[256 + j];
    }
}

// ---------------- launcher ----------------
extern "C" void kernel_launch(void* const* d_in, const int* in_sizes, int n_in,
                              void* d_out, int out_size, void* d_ws, size_t ws_size,
                              hipStream_t stream) {
    const int*   X1 = (const int*)d_in[0];
    const int*   X2 = (const int*)d_in[1];
    const float* W  = (const float*)d_in[2];
    const float* b  = (const float*)d_in[3];
    const float* wp = (const float*)d_in[4];
    const float* a  = (const float*)d_in[5];
    float* out = (float*)d_out;

    char* ws = (char*)d_ws;
    unsigned short* Tb    = (unsigned short*)(ws + 0);         //    458,752
    float*          Tdiag = (float*)(ws + 458752);             //     49,152
    float*          w32   = (float*)(ws + 507904);             //  1,048,576
    unsigned short* wswz  = (unsigned short*)(ws + 1556480);   //    524,288
    float*          kinv  = (float*)(ws + 2080768);            //      2,048
    uint8_t*        X8    = (uint8_t*)(ws + 2082816);          //    262,144
    unsigned short* Abz   = (unsigned short*)(ws + 2344960);   // 11,010,048
    unsigned short* Wbz   = (unsigned short*)(ws + 13355008);  // 57,802,752
    float*          Ep    = (float*)(ws + 71157760);           // 66,060,288 (end 137,218,048)

    prep_kernel<<<PB_TOTAL, 256, 0, stream>>>(X1, X2, W, wp, X8, w32, wswz, Wbz, Abz);
    e_mfma_v6<<<1008, 256, 0, stream>>>(Abz, Wbz, Ep);
    t_kernel<<<512, 256, 0, stream>>>(Ep, b, Tb, Tdiag);
    k_kernel<<<128, 512, 0, stream>>>(X8, Tdiag, w32, kinv);
    k4_kernel<<<dim3(64, 16), 1024, 0, stream>>>(X8, Tb, wswz, kinv, a, out);
}

// Round 9
// 321.759 us; speedup vs baseline: 1.3659x; 1.3659x over previous
//
#include <hip/hip_runtime.h>
#include <cstdint>
#include <cstddef>

// ---------------- types / helpers ----------------
typedef __attribute__((ext_vector_type(8))) __bf16 bf16x8;
typedef __attribute__((ext_vector_type(4))) __bf16 bf16x4;
typedef __attribute__((ext_vector_type(4))) float f32x4;
typedef __attribute__((ext_vector_type(16))) float f32x16;

__device__ __forceinline__ unsigned short f2b(float x) {
    uint32_t u = __float_as_uint(x);
    u += 0x7FFFu + ((u >> 16) & 1u);   // RNE
    return (unsigned short)(u >> 16);
}
__device__ __forceinline__ float b2f(unsigned short h) {
    return __uint_as_float(((uint32_t)h) << 16);
}

// async global->LDS, 16B per lane. LDS dest is wave-uniform base (+lane*16 by HW).
__device__ __forceinline__ void gl16(const unsigned short* g, unsigned short* l) {
    __builtin_amdgcn_global_load_lds((const __attribute__((address_space(1))) uint32_t*)g,
                                     (__attribute__((address_space(3))) uint32_t*)l, 16, 0, 0);
}

#define L_SEQ 512
#define N_AA 21
#define DDIM 128
#define NCOL 2688        // 21*128
#define NSEQ 512         // 256 + 256
#define TBSTRIDE 448     // Tb row stride (u16), 441 used
#define KTOT 10752       // 512*21
#define ZCH 8            // k-chunks (partial-slab count)
#define KBTOT 672        // 10752/16 k-subtiles
#define KBCH 84          // 672/8 k-subtiles per chunk

// block-range sizes inside prep_kernel
#define PB_WBZ   2688    // 672 kb x 4 col-windows (LDS transpose-staged)
#define PB_REPACK 1024
#define PB_WBUILD 1024
#define PB_ABZ   2688    // 16*672/4 fragments
#define PB_TOTAL (PB_WBZ + PB_REPACK + PB_WBUILD + PB_ABZ)

#define WS_PAD 684       // LDS row stride (u16) for the W tile
#define SH_PAD 516       // Sh row stride (u16): 258 dw, gcd(258,32)=2 -> 2-way (free) on b64

// ---------------- kernel 1: fused prologue ----------------
// Independent sub-jobs, dispatched by blockIdx range:
//   [0, 2688)      : W fp32 -> Wbz bf16 fragment-swizzled (LDS transpose-staged,
//                    both global read and write fully contiguous)
//   [+1024)        : X1/X2 int32 -> X8 u8
//   [+1024)        : w32 = sigmoid(wm), wswz = bf16 MFMA-frag order
//   [+2688)        : one-hot A -> Abz bf16 fragment-swizzled (reads X1/X2)
__global__ __launch_bounds__(256) void prep_kernel(const int* X1, const int* X2,
                                                   const float* W, const float* wp,
                                                   uint8_t* X8,
                                                   float* w32, unsigned short* wswz,
                                                   unsigned short* Wbz, unsigned short* Abz) {
    __shared__ unsigned short Ws[16 * WS_PAD];   // 21.9 KB, only used by the Wbz job
    int bid = blockIdx.x;
    int t = threadIdx.x;
    if (bid < PB_WBZ) {
        int kb = bid >> 2, cw = bid & 3;         // 16 rows starting r0, 672-col window c0
        int r0 = kb * 16, c0 = cw * 672;
        // phase 1: contiguous W read (float4/lane), bf16-convert into LDS tile [16][WS_PAD]
        for (int e = t; e < 16 * 168; e += 256) {
            int ri = e / 168, c4 = e - ri * 168;
            float4 v = *(const float4*)(W + (size_t)(r0 + ri) * NCOL + c0 + c4 * 4);
            union { ushort4 q; unsigned short s[4]; } o;
            o.s[0] = f2b(v.x); o.s[1] = f2b(v.y); o.s[2] = f2b(v.z); o.s[3] = f2b(v.w);
            *(ushort4*)&Ws[ri * WS_PAD + c4 * 4] = o.q;
        }
        __syncthreads();
        // phase 2: gather fragment order from LDS, contiguous Wbz write (uint4/lane)
        for (int e = t; e < 21 * 64; e += 256) {
            int fi = e >> 6, sl = e & 63;
            int lr = sl & 31, hf = sl >> 5;
            union { uint4 q; unsigned short s[8]; } o;
#pragma unroll
            for (int j = 0; j < 8; ++j) o.s[j] = Ws[(hf * 8 + j) * WS_PAD + fi * 32 + lr];
            int cb = cw * 21 + fi;
            *(uint4*)&Wbz[((size_t)cb * KBTOT + kb) * 512 + sl * 8] = o.q;
        }
        return;
    }
    bid -= PB_WBZ;
    if (bid < PB_REPACK) {
        int e = bid * 256 + t;             // 262,144
        if (e < 131072) X8[e] = (uint8_t)X1[e];
        else            X8[e] = (uint8_t)X2[e - 131072];
        return;
    }
    bid -= PB_REPACK;
    if (bid < PB_WBUILD) {
        int e = bid * 256 + t;             // 262,144 = 512*512
        int p = e >> 9, q = e & 511;
        float x = 0.0f;
        if (p > q)      x = wp[p * (p - 1) / 2 + q];
        else if (p < q) x = wp[q * (q - 1) / 2 + p];
        float s = 1.0f / (1.0f + expf(-x));
        w32[e] = s;
        int nb = p >> 5, lr = p & 31;
        int kb = q >> 4, hf = (q >> 3) & 1, j = q & 7;
        wswz[(size_t)((nb * 32 + kb) * 512) + (hf * 32 + lr) * 8 + j] = f2b(s);
        return;
    }
    bid -= PB_WBUILD;
    {
        // Abz fragment (mb,kb): lane (hf,lr) holds onehot(X[mb*32+lr], k=kb*16+hf*8+j)
        int f = bid * 4 + (t >> 6);        // 0..10751
        int lane = t & 63, lr = lane & 31, hf = lane >> 5;
        int mb = f / KBTOT, kb = f - mb * KBTOT;
        int m = mb * 32 + lr;
        const int* Xrow = (m < 256) ? (X1 + (size_t)m * L_SEQ) : (X2 + (size_t)(m - 256) * L_SEQ);
        int k0 = kb * 16 + hf * 8;
        union { uint4 q; unsigned short s[8]; } o;
#pragma unroll
        for (int j = 0; j < 8; ++j) {
            int k = k0 + j;
            int l = k / N_AA;
            int aa = k - l * N_AA;
            o.s[j] = (Xrow[l] == aa) ? (unsigned short)0x3F80u : (unsigned short)0u;
        }
        *(uint4*)&Abz[(size_t)f * 512 + lane * 8] = o.q;
    }
}

// ---------------- kernel 2: Ep[kz] = A @ W (k-chunk partial) — LDS ring, PLAIN STORES ---
// 672 blocks (21 c x 4 m x 8 k), XCD-swizzled, 4 waves. Per K-step the block stages its
// 8 unique fragments (4 A + 4 B, 8 KB) once via global_load_lds into a 4-deep ring;
// counted vmcnt(6) keeps 3 K-steps of loads in flight across raw s_barriers.
__global__ __launch_bounds__(256, 4) void e_mfma_v5(const unsigned short* Abz, const unsigned short* Wbz, float* Ep) {
    __shared__ unsigned short lds[4 * 8 * 512];   // 4 bufs x 8 frags x 1024 B = 32 KB

    int lin = blockIdx.x;
    int s = ((lin & 7) * 84) + (lin >> 3);    // bijective XCD swizzle (672 % 8 == 0)
    int cx = s % 21;
    int rem = s / 21;                          // 0..31
    int my = rem & 3;
    int kz = rem >> 2;                         // 0..7

    int t = threadIdx.x, wid = t >> 6, lane = t & 63;
    int lr = lane & 31, hf = lane >> 5;
    int kb0 = kz * KBCH;

    const unsigned short* Aw = Abz + ((size_t)((my * 4 + wid) * KBTOT + kb0)) * 512 + lane * 8;
    const unsigned short* Bw = Wbz + ((size_t)((cx * 4 + wid) * KBTOT + kb0)) * 512 + lane * 8;
    unsigned short* La = &lds[wid * 512];
    unsigned short* Lb = &lds[(4 + wid) * 512];

#define STG(buf_, kb_) do { \
        gl16(Aw + (size_t)(kb_) * 512, La + (buf_) * 4096); \
        gl16(Bw + (size_t)(kb_) * 512, Lb + (buf_) * 4096); \
    } while (0)

    int alo = (wid & 1) * 2;          // A frag slots this wave consumes
    int blo = 4 + (wid >> 1) * 2;     // B frag slots

    f32x16 acc00, acc01, acc10, acc11;
#pragma unroll
    for (int r = 0; r < 16; ++r) { acc00[r] = 0.f; acc01[r] = 0.f; acc10[r] = 0.f; acc11[r] = 0.f; }

#define COMPUTE(kb_) do { \
        const unsigned short* base = &lds[((kb_) & 3) * 4096]; \
        bf16x8 a0 = *(const bf16x8*)(base + (alo + 0) * 512 + lane * 8); \
        bf16x8 a1 = *(const bf16x8*)(base + (alo + 1) * 512 + lane * 8); \
        bf16x8 b0 = *(const bf16x8*)(base + (blo + 0) * 512 + lane * 8); \
        bf16x8 b1 = *(const bf16x8*)(base + (blo + 1) * 512 + lane * 8); \
        acc00 = __builtin_amdgcn_mfma_f32_32x32x16_bf16(a0, b0, acc00, 0, 0, 0); \
        acc01 = __builtin_amdgcn_mfma_f32_32x32x16_bf16(a0, b1, acc01, 0, 0, 0); \
        acc10 = __builtin_amdgcn_mfma_f32_32x32x16_bf16(a1, b0, acc10, 0, 0, 0); \
        acc11 = __builtin_amdgcn_mfma_f32_32x32x16_bf16(a1, b1, acc11, 0, 0, 0); \
    } while (0)

    // prologue: stage kb=0,1,2 (6 loads/wave outstanding)
    STG(0, 0); STG(1, 1); STG(2, 2);

#pragma unroll 1
    for (int kb = 0; kb < KBCH - 3; ++kb) {
        STG((kb + 3) & 3, kb + 3);                      // overwrite buffer read at kb-1 (fenced below)
        asm volatile("s_waitcnt vmcnt(6)" ::: "memory"); // own kb loads landed; 3 steps stay in flight
        __builtin_amdgcn_s_barrier();                    // all waves' kb loads landed
        __builtin_amdgcn_sched_barrier(0);
        COMPUTE(kb);
        __builtin_amdgcn_sched_barrier(0);
        __builtin_amdgcn_s_barrier();                    // all waves done reading buf[kb&3] before restage
    }
    // tail: kb = KBCH-3 .. KBCH-1 (no more staging)
    asm volatile("s_waitcnt vmcnt(4)" ::: "memory");
    __builtin_amdgcn_s_barrier();
    __builtin_amdgcn_sched_barrier(0);
    COMPUTE(KBCH - 3);
    asm volatile("s_waitcnt vmcnt(2)" ::: "memory");
    __builtin_amdgcn_s_barrier();
    __builtin_amdgcn_sched_barrier(0);
    COMPUTE(KBCH - 2);
    asm volatile("s_waitcnt vmcnt(0)" ::: "memory");
    __builtin_amdgcn_s_barrier();
    __builtin_amdgcn_sched_barrier(0);
    COMPUTE(KBCH - 1);

#undef STG
#undef COMPUTE

    int mb0 = my * 4 + (wid & 1) * 2;        // m-fragment index (32-row units)
    int cb0 = cx * 4 + (wid >> 1) * 2;       // c-fragment index (32-col units)
    float* slab = Ep + (size_t)kz * NSEQ * NCOL;
#pragma unroll
    for (int r = 0; r < 16; ++r) {
        int row = (r & 3) + 8 * (r >> 2) + 4 * hf;
        float* base = slab + (size_t)(mb0 * 32 + row) * NCOL + cb0 * 32 + lr;
        base[0] = acc00[r];
        base[32] = acc01[r];
        base[(size_t)32 * NCOL] = acc10[r];
        base[(size_t)32 * NCOL + 32] = acc11[r];
    }
}

// ---------------- kernel 3: T[n] = E[n] @ E[n]^T, E[n] = sum_z Ep[z][n] + bias --------
__global__ __launch_bounds__(256) void t_kernel(const float* Ep, const float* bvec,
                                                unsigned short* Tb, float* Tdiag) {
    __shared__ float4 Es4[21 * 33];
    int t = threadIdx.x, n = blockIdx.x;
    for (int idx = t; idx < 672; idx += 256) {          // 672 float4 = 2688 cols
        const float4* bp = (const float4*)(bvec + idx * 4);
        float4 acc = *bp;
#pragma unroll
        for (int z = 0; z < ZCH; ++z) {
            float4 v = *(const float4*)(Ep + ((size_t)z * NSEQ + n) * NCOL + idx * 4);
            acc.x += v.x; acc.y += v.y; acc.z += v.z; acc.w += v.w;
        }
        int r = idx >> 5, d = idx & 31;
        Es4[r * 33 + d] = acc;
    }
    __syncthreads();
    for (int e = t; e < 441; e += 256) {
        int r = e / 21, c = e - r * 21;
        const float4* ar = &Es4[r * 33];
        const float4* br = &Es4[c * 33];
        float s = 0.f;
#pragma unroll 8
        for (int d = 0; d < 32; ++d) {
            float4 a = ar[d], b = br[d];
            s += a.x * b.x + a.y * b.y + a.z * b.z + a.w * b.w;
        }
        Tb[(size_t)n * TBSTRIDE + e] = f2b(0.5f * s);
        if (r == c) Tdiag[n * 24 + r] = s;
    }
}

// ---------------- kernel 4: kinv — coalesced wave-per-row bilinear form ----------------
__global__ __launch_bounds__(512) void k_kernel(const uint8_t* X8, const float* Tdiag, const float* w32, float* kinv) {
    __shared__ __align__(16) float dvec[4][512];
    __shared__ float Td[4][21];
    __shared__ float wred[4][8];
    int t = threadIdx.x, n0 = blockIdx.x * 4;
    if (t < 84) Td[t / 21][t % 21] = Tdiag[(size_t)(n0 + t / 21) * 24 + (t % 21)];
    __syncthreads();
    for (int e = t; e < 2048; e += 512) {
        int nn = e >> 9, l = e & 511;
        dvec[nn][l] = Td[nn][X8[(size_t)(n0 + nn) * 512 + l]];
    }
    __syncthreads();
    int wid = t >> 6, lane = t & 63;
    int q0 = lane * 8;

    float4 dA0 = *(const float4*)&dvec[0][q0], dA1 = *(const float4*)&dvec[0][q0 + 4];
    float4 dB0 = *(const float4*)&dvec[1][q0], dB1 = *(const float4*)&dvec[1][q0 + 4];
    float4 dC0 = *(const float4*)&dvec[2][q0], dC1 = *(const float4*)&dvec[2][q0 + 4];
    float4 dD0 = *(const float4*)&dvec[3][q0], dD1 = *(const float4*)&dvec[3][q0 + 4];

    float4 rA0 = {0,0,0,0}, rA1 = {0,0,0,0}, rB0 = {0,0,0,0}, rB1 = {0,0,0,0};
    float4 rC0 = {0,0,0,0}, rC1 = {0,0,0,0}, rD0 = {0,0,0,0}, rD1 = {0,0,0,0};

#define FMA4(R, W, S) do { (R).x += (W).x * (S); (R).y += (W).y * (S); (R).z += (W).z * (S); (R).w += (W).w * (S); } while (0)
    for (int p = wid; p < 512; p += 8) {
        const float4* wr = (const float4*)(w32 + (size_t)p * 512 + q0);
        float4 w0v = wr[0], w1v = wr[1];
        float a = dvec[0][p], b = dvec[1][p], c = dvec[2][p], d = dvec[3][p];
        FMA4(rA0, w0v, a); FMA4(rA1, w1v, a);
        FMA4(rB0, w0v, b); FMA4(rB1, w1v, b);
        FMA4(rC0, w0v, c); FMA4(rC1, w1v, c);
        FMA4(rD0, w0v, d); FMA4(rD1, w1v, d);
    }
#undef FMA4

#define DOT8(R0, R1, D0, D1) ((R0).x*(D0).x + (R0).y*(D0).y + (R0).z*(D0).z + (R0).w*(D0).w + \
                              (R1).x*(D1).x + (R1).y*(D1).y + (R1).z*(D1).z + (R1).w*(D1).w)
    float s0 = DOT8(rA0, rA1, dA0, dA1);
    float s1 = DOT8(rB0, rB1, dB0, dB1);
    float s2 = DOT8(rC0, rC1, dC0, dC1);
    float s3 = DOT8(rD0, rD1, dD0, dD1);
#undef DOT8

#pragma unroll
    for (int off = 1; off < 64; off <<= 1) {
        s0 += __shfl_xor(s0, off);
        s1 += __shfl_xor(s1, off);
        s2 += __shfl_xor(s2, off);
        s3 += __shfl_xor(s3, off);
    }
    if (lane == 0) { wred[0][wid] = s0; wred[1][wid] = s1; wred[2][wid] = s2; wred[3][wid] = s3; }
    __syncthreads();
    if (t < 4) {
        float kk = 0.f;
#pragma unroll
        for (int w = 0; w < 8; ++w) kk += wred[t][w];
        kinv[n0 + t] = 1.0f / sqrtf(kk);
    }
}

// ---------------- kernel 5: main pair GEMM — 8 waves (512 thr), bf16 Tb staging ----------
// Round-8 lesson: keep LDS <= ~53 KB for 3 blocks/CU. Change vs round 7: SH_PAD 520->516
// (258 dw, gcd(258,32)=2 -> 2-way free) and A-fragment loads as 2x ds_read_b64 (8B-aligned
// at stride 516; bf16x4 type prevents illegal b128 fusion). Kills the ~4.4M-cycle 4-way
// conflict on the A reads.
__global__ __launch_bounds__(512, 6) void k4_kernel(const uint8_t* X8, const unsigned short* Tb,
                                                    const unsigned short* wswz, const float* kinv,
                                                    const float* Ainp, float* out) {
    __shared__ unsigned short Sh[32 * SH_PAD];
    __shared__ unsigned short Ts1h[4 * TBSTRIDE];
    __shared__ unsigned short Ts2h[8 * TBSTRIDE];
    __shared__ unsigned short A21[4 * 512];
    __shared__ uint8_t Xs2[8 * 512];
    __shared__ float Kacc[8][32];

    int t = threadIdx.x;
    int i0 = blockIdx.x * 4;
    int j0 = blockIdx.y * 8;

    for (int e = t; e < 4 * 512; e += 512)
        A21[e] = (unsigned short)(21 * X8[(size_t)(i0 + (e >> 9)) * 512 + (e & 511)]);
    {
        const uint32_t* s2 = (const uint32_t*)(X8 + (size_t)(256 + j0) * 512);
        uint32_t* d2 = (uint32_t*)Xs2;
        for (int e = t; e < 1024; e += 512) d2[e] = s2[e];
    }
    {
        // Tb rows are already 0.5*T in bf16 — straight u32 copies (448 u16 = 224 u32 per row)
        uint32_t* d1 = (uint32_t*)Ts1h;
        for (int e = t; e < 4 * 224; e += 512) {
            int r = e / 224, w = e - r * 224;
            d1[e] = ((const uint32_t*)(Tb + (size_t)(i0 + r) * TBSTRIDE))[w];
        }
        uint32_t* d2 = (uint32_t*)Ts2h;
        for (int e = t; e < 8 * 224; e += 512) {
            int r = e / 224, w = e - r * 224;
            d2[e] = ((const uint32_t*)(Tb + (size_t)(256 + j0 + r) * TBSTRIDE))[w];
        }
    }
    __syncthreads();

    // build S tile: 4 elems per thread-iter, packed u64 write (8B-aligned at SH_PAD=516)
    for (int e4 = t; e4 < 32 * 128; e4 += 512) {
        int pr = e4 >> 7, p = (e4 & 127) * 4;
        int ti = pr >> 3, tj = pr & 7;
        uint64_t a4 = *(const uint64_t*)&A21[ti * 512 + p];   // 4 u16 (a*21)
        uint32_t b4 = *(const uint32_t*)&Xs2[tj * 512 + p];   // 4 u8
        const unsigned short* T1 = &Ts1h[ti * TBSTRIDE];
        const unsigned short* T2 = &Ts2h[tj * TBSTRIDE];
        uint64_t outw = 0;
#pragma unroll
        for (int u = 0; u < 4; ++u) {
            int idx = (int)((a4 >> (16 * u)) & 0xFFFFu) + (int)((b4 >> (8 * u)) & 0xFFu);
            float v = b2f(T1[idx]) + b2f(T2[idx]);
            outw |= (uint64_t)f2b(v) << (16 * u);
        }
        *(uint64_t*)&Sh[pr * SH_PAD + p] = outw;
    }
    __syncthreads();

    int wid = t >> 6, lane = t & 63;
    int lr = lane & 31, hf = lane >> 5;
    int n_base = wid * 64;

    const unsigned short* Sa = &Sh[lr * SH_PAD + hf * 8];
    const unsigned short* Bz0 = wswz + (size_t)((wid * 2 + 0) * 32) * 512 + lane * 8;
    const unsigned short* Bz1 = wswz + (size_t)((wid * 2 + 1) * 32) * 512 + lane * 8;

    f32x16 acc0, acc1;
#pragma unroll
    for (int j = 0; j < 16; ++j) { acc0[j] = 0.f; acc1[j] = 0.f; }

#pragma unroll 2
    for (int kt = 0; kt < 32; ++kt) {
        union { bf16x8 v; bf16x4 h[2]; } av;
        av.h[0] = *(const bf16x4*)(Sa + kt * 16);
        av.h[1] = *(const bf16x4*)(Sa + kt * 16 + 4);
        bf16x8 bv0 = *(const bf16x8*)(Bz0 + kt * 512);
        bf16x8 bv1 = *(const bf16x8*)(Bz1 + kt * 512);
        acc0 = __builtin_amdgcn_mfma_f32_32x32x16_bf16(av.v, bv0, acc0, 0, 0, 0);
        acc1 = __builtin_amdgcn_mfma_f32_32x32x16_bf16(av.v, bv1, acc1, 0, 0, 0);
    }

    float prow[16];
#pragma unroll
    for (int r = 0; r < 16; ++r) {
        int row = (r & 3) + 8 * (r >> 2) + 4 * hf;
        float v = acc0[r] * b2f(Sh[row * SH_PAD + (n_base + lr)]);
        v      += acc1[r] * b2f(Sh[row * SH_PAD + (n_base + 32 + lr)]);
        prow[r] = v;
    }
#pragma unroll
    for (int r = 0; r < 16; ++r) {
        float v = prow[r];
        v += __shfl_xor(v, 1);
        v += __shfl_xor(v, 2);
        v += __shfl_xor(v, 4);
        v += __shfl_xor(v, 8);
        v += __shfl_xor(v, 16);
        if (lr == 0) {
            int row = (r & 3) + 8 * (r >> 2) + 4 * hf;
            Kacc[wid][row] = v;
        }
    }
    __syncthreads();

    if (t < 32) {
        float K = Kacc[0][t] + Kacc[1][t] + Kacc[2][t] + Kacc[3][t]
                + Kacc[4][t] + Kacc[5][t] + Kacc[6][t] + Kacc[7][t];
        int ti = t >> 3, tj = t & 7;
        int i = i0 + ti, j = j0 + tj;
        float a0 = Ainp[0];
        out[i * 256 + j] = a0 * a0 * K * kinv[i] * kinv[256 + j];
    }
}

// ---------------- launcher ----------------
extern "C" void kernel_launch(void* const* d_in, const int* in_sizes, int n_in,
                              void* d_out, int out_size, void* d_ws, size_t ws_size,
                              hipStream_t stream) {
    const int*   X1 = (const int*)d_in[0];
    const int*   X2 = (const int*)d_in[1];
    const float* W  = (const float*)d_in[2];
    const float* b  = (const float*)d_in[3];
    const float* wp = (const float*)d_in[4];
    const float* a  = (const float*)d_in[5];
    float* out = (float*)d_out;

    char* ws = (char*)d_ws;
    unsigned short* Tb    = (unsigned short*)(ws + 0);         //    458,752
    float*          Tdiag = (float*)(ws + 458752);             //     49,152
    float*          w32   = (float*)(ws + 507904);             //  1,048,576
    unsigned short* wswz  = (unsigned short*)(ws + 1556480);   //    524,288
    float*          kinv  = (float*)(ws + 2080768);            //      2,048
    uint8_t*        X8    = (uint8_t*)(ws + 2082816);          //    262,144
    unsigned short* Abz   = (unsigned short*)(ws + 2344960);   // 11,010,048
    unsigned short* Wbz   = (unsigned short*)(ws + 13355008);  // 57,802,752
    float*          Ep    = (float*)(ws + 71157760);           // 44,040,192 (end 115,197,952)

    prep_kernel<<<PB_TOTAL, 256, 0, stream>>>(X1, X2, W, wp, X8, w32, wswz, Wbz, Abz);
    e_mfma_v5<<<672, 256, 0, stream>>>(Abz, Wbz, Ep);
    t_kernel<<<512, 256, 0, stream>>>(Ep, b, Tb, Tdiag);
    k_kernel<<<128, 512, 0, stream>>>(X8, Tdiag, w32, kinv);
    k4_kernel<<<dim3(64, 32), 512, 0, stream>>>(X8, Tb, wswz, kinv, a, out);
}

// Round 10
// 318.976 us; speedup vs baseline: 1.3778x; 1.0087x over previous
//
#include <hip/hip_runtime.h>
#include <cstdint>
#include <cstddef>

// ---------------- types / helpers ----------------
typedef __attribute__((ext_vector_type(8))) __bf16 bf16x8;
typedef __attribute__((ext_vector_type(4))) __bf16 bf16x4;
typedef __attribute__((ext_vector_type(4))) float f32x4;
typedef __attribute__((ext_vector_type(16))) float f32x16;

__device__ __forceinline__ unsigned short f2b(float x) {
    uint32_t u = __float_as_uint(x);
    u += 0x7FFFu + ((u >> 16) & 1u);   // RNE
    return (unsigned short)(u >> 16);
}
__device__ __forceinline__ float b2f(unsigned short h) {
    return __uint_as_float(((uint32_t)h) << 16);
}

// async global->LDS, 16B per lane. LDS dest is wave-uniform base (+lane*16 by HW).
__device__ __forceinline__ void gl16(const void* g, void* l) {
    __builtin_amdgcn_global_load_lds((const __attribute__((address_space(1))) uint32_t*)g,
                                     (__attribute__((address_space(3))) uint32_t*)l, 16, 0, 0);
}

#define L_SEQ 512
#define N_AA 21
#define DDIM 128
#define NCOL 2688        // 21*128
#define NSEQ 512         // 256 + 256
#define TBSTRIDE 448     // Tb row stride (u16), 441 used
#define KTOT 10752       // 512*21
#define ZCH 8            // k-chunks (partial-slab count)
#define KBTOT 672        // 10752/16 k-subtiles
#define KBCH 84          // 672/8 k-subtiles per chunk

// block-range sizes inside prep_kernel
#define PB_WBZ   2688    // 672 kb x 4 col-windows (gl16-staged fp32 tile)
#define PB_REPACK 1024
#define PB_WBUILD 1024
#define PB_ABZ   2688    // 16*672/4 fragments
#define PB_TOTAL (PB_WBZ + PB_REPACK + PB_WBUILD + PB_ABZ)

#define SH_PAD 516       // Sh row stride (u16): 258 dw, gcd(258,32)=2 -> 2-way (free) on b64

// ---------------- kernel 1: fused prologue ----------------
// Independent sub-jobs, dispatched by blockIdx range:
//   [0, 2688)      : W fp32 -> Wbz bf16 fragment-swizzled. Round-9 diagnosis: old
//                    phase-1 had ~1 outstanding load/wave (MLP-bound, 2 TB/s). Now the
//                    16x672 fp32 tile is staged via global_load_lds — all ~10 loads per
//                    wave issued fire-and-forget. fp32 tile unpadded is conflict-free on
//                    the phase-2 read (cols 672 ≡ 0 mod 32; half-waves 2-way = free).
//   [+1024)        : X1/X2 int32 -> X8 u8
//   [+1024)        : w32 = sigmoid(wm), wswz = bf16 MFMA-frag order
//   [+2688)        : one-hot A -> Abz bf16 fragment-swizzled (2 X reads, was 8)
__global__ __launch_bounds__(256) void prep_kernel(const int* X1, const int* X2,
                                                   const float* W, const float* wp,
                                                   uint8_t* X8,
                                                   float* w32, unsigned short* wswz,
                                                   unsigned short* Wbz, unsigned short* Abz) {
    __shared__ float Wf[16 * 672];               // 43 KB, only used by the Wbz job
    int bid = blockIdx.x;
    int t = threadIdx.x;
    if (bid < PB_WBZ) {
        int kb = bid >> 2, cw = bid & 3;         // 16 rows starting r0, 672-col window c0
        int r0 = kb * 16, c0 = cw * 672;
        // phase 1: stage 16x672 fp32 tile via gl16. Tile byte g = i*1024 + lane*16;
        // row = g/2688 (rows are 2688 B = 16B-multiple, no straddle), colb = g%2688.
        {
            int wid = t >> 6, lane = t & 63;
            const char* Wbase = (const char*)(W + (size_t)r0 * NCOL + c0);
            for (int i = wid; i < 42; i += 4) {
                int g = i * 1024 + lane * 16;
                int row = g / 2688;
                int colb = g - row * 2688;
                gl16(Wbase + (size_t)row * (NCOL * 4) + colb, (char*)Wf + i * 1024);
            }
        }
        asm volatile("s_waitcnt vmcnt(0)" ::: "memory");
        __syncthreads();
        // phase 2: gather fragment order from fp32 LDS, convert, contiguous uint4 write
        for (int e = t; e < 21 * 64; e += 256) {
            int fi = e >> 6, sl = e & 63;
            int lr = sl & 31, hf = sl >> 5;
            union { uint4 q; unsigned short s[8]; } o;
#pragma unroll
            for (int j = 0; j < 8; ++j) o.s[j] = f2b(Wf[(hf * 8 + j) * 672 + fi * 32 + lr]);
            int cb = cw * 21 + fi;
            *(uint4*)&Wbz[((size_t)cb * KBTOT + kb) * 512 + sl * 8] = o.q;
        }
        return;
    }
    bid -= PB_WBZ;
    if (bid < PB_REPACK) {
        int e = bid * 256 + t;             // 262,144
        if (e < 131072) X8[e] = (uint8_t)X1[e];
        else            X8[e] = (uint8_t)X2[e - 131072];
        return;
    }
    bid -= PB_REPACK;
    if (bid < PB_WBUILD) {
        int e = bid * 256 + t;             // 262,144 = 512*512
        int p = e >> 9, q = e & 511;
        float x = 0.0f;
        if (p > q)      x = wp[p * (p - 1) / 2 + q];
        else if (p < q) x = wp[q * (q - 1) / 2 + p];
        float s = 1.0f / (1.0f + expf(-x));
        w32[e] = s;
        int nb = p >> 5, lr = p & 31;
        int kb = q >> 4, hf = (q >> 3) & 1, j = q & 7;
        wswz[(size_t)((nb * 32 + kb) * 512) + (hf * 32 + lr) * 8 + j] = f2b(s);
        return;
    }
    bid -= PB_WBUILD;
    {
        // Abz fragment (mb,kb): lane (hf,lr) holds onehot(X[mb*32+lr], k=kb*16+hf*8+j)
        // k0..k0+7 spans at most two l values -> 2 X reads instead of 8.
        int f = bid * 4 + (t >> 6);        // 0..10751
        int lane = t & 63, lr = lane & 31, hf = lane >> 5;
        int mb = f / KBTOT, kb = f - mb * KBTOT;
        int m = mb * 32 + lr;
        const int* Xrow = (m < 256) ? (X1 + (size_t)m * L_SEQ) : (X2 + (size_t)(m - 256) * L_SEQ);
        int k0 = kb * 16 + hf * 8;
        int l0 = k0 / N_AA;
        int x0 = Xrow[l0];
        int x1 = (l0 < L_SEQ - 1) ? Xrow[l0 + 1] : -1;
        union { uint4 q; unsigned short s[8]; } o;
#pragma unroll
        for (int j = 0; j < 8; ++j) {
            int k = k0 + j;
            int l = k / N_AA;
            int aa = k - l * N_AA;
            int x = (l == l0) ? x0 : x1;
            o.s[j] = (x == aa) ? (unsigned short)0x3F80u : (unsigned short)0u;
        }
        *(uint4*)&Abz[(size_t)f * 512 + lane * 8] = o.q;
    }
}

// ---------------- kernel 2: Ep[kz] = A @ W (k-chunk partial) — LDS ring, PLAIN STORES ---
// 672 blocks (21 c x 4 m x 8 k), XCD-swizzled, 4 waves. Per K-step the block stages its
// 8 unique fragments (4 A + 4 B, 8 KB) once via global_load_lds into a 4-deep ring;
// counted vmcnt(6) keeps 3 K-steps of loads in flight across raw s_barriers.
__global__ __launch_bounds__(256, 4) void e_mfma_v5(const unsigned short* Abz, const unsigned short* Wbz, float* Ep) {
    __shared__ unsigned short lds[4 * 8 * 512];   // 4 bufs x 8 frags x 1024 B = 32 KB

    int lin = blockIdx.x;
    int s = ((lin & 7) * 84) + (lin >> 3);    // bijective XCD swizzle (672 % 8 == 0)
    int cx = s % 21;
    int rem = s / 21;                          // 0..31
    int my = rem & 3;
    int kz = rem >> 2;                         // 0..7

    int t = threadIdx.x, wid = t >> 6, lane = t & 63;
    int lr = lane & 31, hf = lane >> 5;
    int kb0 = kz * KBCH;

    const unsigned short* Aw = Abz + ((size_t)((my * 4 + wid) * KBTOT + kb0)) * 512 + lane * 8;
    const unsigned short* Bw = Wbz + ((size_t)((cx * 4 + wid) * KBTOT + kb0)) * 512 + lane * 8;
    unsigned short* La = &lds[wid * 512];
    unsigned short* Lb = &lds[(4 + wid) * 512];

#define STG(buf_, kb_) do { \
        gl16(Aw + (size_t)(kb_) * 512, La + (buf_) * 4096); \
        gl16(Bw + (size_t)(kb_) * 512, Lb + (buf_) * 4096); \
    } while (0)

    int alo = (wid & 1) * 2;          // A frag slots this wave consumes
    int blo = 4 + (wid >> 1) * 2;     // B frag slots

    f32x16 acc00, acc01, acc10, acc11;
#pragma unroll
    for (int r = 0; r < 16; ++r) { acc00[r] = 0.f; acc01[r] = 0.f; acc10[r] = 0.f; acc11[r] = 0.f; }

#define COMPUTE(kb_) do { \
        const unsigned short* base = &lds[((kb_) & 3) * 4096]; \
        bf16x8 a0 = *(const bf16x8*)(base + (alo + 0) * 512 + lane * 8); \
        bf16x8 a1 = *(const bf16x8*)(base + (alo + 1) * 512 + lane * 8); \
        bf16x8 b0 = *(const bf16x8*)(base + (blo + 0) * 512 + lane * 8); \
        bf16x8 b1 = *(const bf16x8*)(base + (blo + 1) * 512 + lane * 8); \
        acc00 = __builtin_amdgcn_mfma_f32_32x32x16_bf16(a0, b0, acc00, 0, 0, 0); \
        acc01 = __builtin_amdgcn_mfma_f32_32x32x16_bf16(a0, b1, acc01, 0, 0, 0); \
        acc10 = __builtin_amdgcn_mfma_f32_32x32x16_bf16(a1, b0, acc10, 0, 0, 0); \
        acc11 = __builtin_amdgcn_mfma_f32_32x32x16_bf16(a1, b1, acc11, 0, 0, 0); \
    } while (0)

    // prologue: stage kb=0,1,2 (6 loads/wave outstanding)
    STG(0, 0); STG(1, 1); STG(2, 2);

#pragma unroll 1
    for (int kb = 0; kb < KBCH - 3; ++kb) {
        STG((kb + 3) & 3, kb + 3);                      // overwrite buffer read at kb-1 (fenced below)
        asm volatile("s_waitcnt vmcnt(6)" ::: "memory"); // own kb loads landed; 3 steps stay in flight
        __builtin_amdgcn_s_barrier();                    // all waves' kb loads landed
        __builtin_amdgcn_sched_barrier(0);
        COMPUTE(kb);
        __builtin_amdgcn_sched_barrier(0);
        __builtin_amdgcn_s_barrier();                    // all waves done reading buf[kb&3] before restage
    }
    // tail: kb = KBCH-3 .. KBCH-1 (no more staging)
    asm volatile("s_waitcnt vmcnt(4)" ::: "memory");
    __builtin_amdgcn_s_barrier();
    __builtin_amdgcn_sched_barrier(0);
    COMPUTE(KBCH - 3);
    asm volatile("s_waitcnt vmcnt(2)" ::: "memory");
    __builtin_amdgcn_s_barrier();
    __builtin_amdgcn_sched_barrier(0);
    COMPUTE(KBCH - 2);
    asm volatile("s_waitcnt vmcnt(0)" ::: "memory");
    __builtin_amdgcn_s_barrier();
    __builtin_amdgcn_sched_barrier(0);
    COMPUTE(KBCH - 1);

#undef STG
#undef COMPUTE

    int mb0 = my * 4 + (wid & 1) * 2;        // m-fragment index (32-row units)
    int cb0 = cx * 4 + (wid >> 1) * 2;       // c-fragment index (32-col units)
    float* slab = Ep + (size_t)kz * NSEQ * NCOL;
#pragma unroll
    for (int r = 0; r < 16; ++r) {
        int row = (r & 3) + 8 * (r >> 2) + 4 * hf;
        float* base = slab + (size_t)(mb0 * 32 + row) * NCOL + cb0 * 32 + lr;
        base[0] = acc00[r];
        base[32] = acc01[r];
        base[(size_t)32 * NCOL] = acc10[r];
        base[(size_t)32 * NCOL + 32] = acc11[r];
    }
}

// ---------------- kernel 3: T[n] = E[n] @ E[n]^T, E[n] = sum_z Ep[z][n] + bias --------
__global__ __launch_bounds__(256) void t_kernel(const float* Ep, const float* bvec,
                                                unsigned short* Tb, float* Tdiag) {
    __shared__ float4 Es4[21 * 33];
    int t = threadIdx.x, n = blockIdx.x;
    for (int idx = t; idx < 672; idx += 256) {          // 672 float4 = 2688 cols
        const float4* bp = (const float4*)(bvec + idx * 4);
        float4 acc = *bp;
#pragma unroll
        for (int z = 0; z < ZCH; ++z) {
            float4 v = *(const float4*)(Ep + ((size_t)z * NSEQ + n) * NCOL + idx * 4);
            acc.x += v.x; acc.y += v.y; acc.z += v.z; acc.w += v.w;
        }
        int r = idx >> 5, d = idx & 31;
        Es4[r * 33 + d] = acc;
    }
    __syncthreads();
    for (int e = t; e < 441; e += 256) {
        int r = e / 21, c = e - r * 21;
        const float4* ar = &Es4[r * 33];
        const float4* br = &Es4[c * 33];
        float s = 0.f;
#pragma unroll 8
        for (int d = 0; d < 32; ++d) {
            float4 a = ar[d], b = br[d];
            s += a.x * b.x + a.y * b.y + a.z * b.z + a.w * b.w;
        }
        Tb[(size_t)n * TBSTRIDE + e] = f2b(0.5f * s);
        if (r == c) Tdiag[n * 24 + r] = s;
    }
}

// ---------------- kernel 4: kinv — coalesced wave-per-row bilinear form ----------------
__global__ __launch_bounds__(512) void k_kernel(const uint8_t* X8, const float* Tdiag, const float* w32, float* kinv) {
    __shared__ __align__(16) float dvec[4][512];
    __shared__ float Td[4][21];
    __shared__ float wred[4][8];
    int t = threadIdx.x, n0 = blockIdx.x * 4;
    if (t < 84) Td[t / 21][t % 21] = Tdiag[(size_t)(n0 + t / 21) * 24 + (t % 21)];
    __syncthreads();
    for (int e = t; e < 2048; e += 512) {
        int nn = e >> 9, l = e & 511;
        dvec[nn][l] = Td[nn][X8[(size_t)(n0 + nn) * 512 + l]];
    }
    __syncthreads();
    int wid = t >> 6, lane = t & 63;
    int q0 = lane * 8;

    float4 dA0 = *(const float4*)&dvec[0][q0], dA1 = *(const float4*)&dvec[0][q0 + 4];
    float4 dB0 = *(const float4*)&dvec[1][q0], dB1 = *(const float4*)&dvec[1][q0 + 4];
    float4 dC0 = *(const float4*)&dvec[2][q0], dC1 = *(const float4*)&dvec[2][q0 + 4];
    float4 dD0 = *(const float4*)&dvec[3][q0], dD1 = *(const float4*)&dvec[3][q0 + 4];

    float4 rA0 = {0,0,0,0}, rA1 = {0,0,0,0}, rB0 = {0,0,0,0}, rB1 = {0,0,0,0};
    float4 rC0 = {0,0,0,0}, rC1 = {0,0,0,0}, rD0 = {0,0,0,0}, rD1 = {0,0,0,0};

#define FMA4(R, W, S) do { (R).x += (W).x * (S); (R).y += (W).y * (S); (R).z += (W).z * (S); (R).w += (W).w * (S); } while (0)
    for (int p = wid; p < 512; p += 8) {
        const float4* wr = (const float4*)(w32 + (size_t)p * 512 + q0);
        float4 w0v = wr[0], w1v = wr[1];
        float a = dvec[0][p], b = dvec[1][p], c = dvec[2][p], d = dvec[3][p];
        FMA4(rA0, w0v, a); FMA4(rA1, w1v, a);
        FMA4(rB0, w0v, b); FMA4(rB1, w1v, b);
        FMA4(rC0, w0v, c); FMA4(rC1, w1v, c);
        FMA4(rD0, w0v, d); FMA4(rD1, w1v, d);
    }
#undef FMA4

#define DOT8(R0, R1, D0, D1) ((R0).x*(D0).x + (R0).y*(D0).y + (R0).z*(D0).z + (R0).w*(D0).w + \
                              (R1).x*(D1).x + (R1).y*(D1).y + (R1).z*(D1).z + (R1).w*(D1).w)
    float s0 = DOT8(rA0, rA1, dA0, dA1);
    float s1 = DOT8(rB0, rB1, dB0, dB1);
    float s2 = DOT8(rC0, rC1, dC0, dC1);
    float s3 = DOT8(rD0, rD1, dD0, dD1);
#undef DOT8

#pragma unroll
    for (int off = 1; off < 64; off <<= 1) {
        s0 += __shfl_xor(s0, off);
        s1 += __shfl_xor(s1, off);
        s2 += __shfl_xor(s2, off);
        s3 += __shfl_xor(s3, off);
    }
    if (lane == 0) { wred[0][wid] = s0; wred[1][wid] = s1; wred[2][wid] = s2; wred[3][wid] = s3; }
    __syncthreads();
    if (t < 4) {
        float kk = 0.f;
#pragma unroll
        for (int w = 0; w < 8; ++w) kk += wred[t][w];
        kinv[n0 + t] = 1.0f / sqrtf(kk);
    }
}

// ---------------- kernel 5: main pair GEMM — 8 waves (512 thr), bf16 Tb staging ----------
__global__ __launch_bounds__(512, 6) void k4_kernel(const uint8_t* X8, const unsigned short* Tb,
                                                    const unsigned short* wswz, const float* kinv,
                                                    const float* Ainp, float* out) {
    __shared__ unsigned short Sh[32 * SH_PAD];
    __shared__ unsigned short Ts1h[4 * TBSTRIDE];
    __shared__ unsigned short Ts2h[8 * TBSTRIDE];
    __shared__ unsigned short A21[4 * 512];
    __shared__ uint8_t Xs2[8 * 512];
    __shared__ float Kacc[8][32];

    int t = threadIdx.x;
    int i0 = blockIdx.x * 4;
    int j0 = blockIdx.y * 8;

    for (int e = t; e < 4 * 512; e += 512)
        A21[e] = (unsigned short)(21 * X8[(size_t)(i0 + (e >> 9)) * 512 + (e & 511)]);
    {
        const uint32_t* s2 = (const uint32_t*)(X8 + (size_t)(256 + j0) * 512);
        uint32_t* d2 = (uint32_t*)Xs2;
        for (int e = t; e < 1024; e += 512) d2[e] = s2[e];
    }
    {
        // Tb rows are already 0.5*T in bf16 — straight u32 copies (448 u16 = 224 u32 per row)
        uint32_t* d1 = (uint32_t*)Ts1h;
        for (int e = t; e < 4 * 224; e += 512) {
            int r = e / 224, w = e - r * 224;
            d1[e] = ((const uint32_t*)(Tb + (size_t)(i0 + r) * TBSTRIDE))[w];
        }
        uint32_t* d2 = (uint32_t*)Ts2h;
        for (int e = t; e < 8 * 224; e += 512) {
            int r = e / 224, w = e - r * 224;
            d2[e] = ((const uint32_t*)(Tb + (size_t)(256 + j0 + r) * TBSTRIDE))[w];
        }
    }
    __syncthreads();

    // build S tile: 4 elems per thread-iter, packed u64 write (8B-aligned at SH_PAD=516)
    for (int e4 = t; e4 < 32 * 128; e4 += 512) {
        int pr = e4 >> 7, p = (e4 & 127) * 4;
        int ti = pr >> 3, tj = pr & 7;
        uint64_t a4 = *(const uint64_t*)&A21[ti * 512 + p];   // 4 u16 (a*21)
        uint32_t b4 = *(const uint32_t*)&Xs2[tj * 512 + p];   // 4 u8
        const unsigned short* T1 = &Ts1h[ti * TBSTRIDE];
        const unsigned short* T2 = &Ts2h[tj * TBSTRIDE];
        uint64_t outw = 0;
#pragma unroll
        for (int u = 0; u < 4; ++u) {
            int idx = (int)((a4 >> (16 * u)) & 0xFFFFu) + (int)((b4 >> (8 * u)) & 0xFFu);
            float v = b2f(T1[idx]) + b2f(T2[idx]);
            outw |= (uint64_t)f2b(v) << (16 * u);
        }
        *(uint64_t*)&Sh[pr * SH_PAD + p] = outw;
    }
    __syncthreads();

    int wid = t >> 6, lane = t & 63;
    int lr = lane & 31, hf = lane >> 5;
    int n_base = wid * 64;

    const unsigned short* Sa = &Sh[lr * SH_PAD + hf * 8];
    const unsigned short* Bz0 = wswz + (size_t)((wid * 2 + 0) * 32) * 512 + lane * 8;
    const unsigned short* Bz1 = wswz + (size_t)((wid * 2 + 1) * 32) * 512 + lane * 8;

    f32x16 acc0, acc1;
#pragma unroll
    for (int j = 0; j < 16; ++j) { acc0[j] = 0.f; acc1[j] = 0.f; }

#pragma unroll 2
    for (int kt = 0; kt < 32; ++kt) {
        union { bf16x8 v; bf16x4 h[2]; } av;
        av.h[0] = *(const bf16x4*)(Sa + kt * 16);
        av.h[1] = *(const bf16x4*)(Sa + kt * 16 + 4);
        bf16x8 bv0 = *(const bf16x8*)(Bz0 + kt * 512);
        bf16x8 bv1 = *(const bf16x8*)(Bz1 + kt * 512);
        acc0 = __builtin_amdgcn_mfma_f32_32x32x16_bf16(av.v, bv0, acc0, 0, 0, 0);
        acc1 = __builtin_amdgcn_mfma_f32_32x32x16_bf16(av.v, bv1, acc1, 0, 0, 0);
    }

    float prow[16];
#pragma unroll
    for (int r = 0; r < 16; ++r) {
        int row = (r & 3) + 8 * (r >> 2) + 4 * hf;
        float v = acc0[r] * b2f(Sh[row * SH_PAD + (n_base + lr)]);
        v      += acc1[r] * b2f(Sh[row * SH_PAD + (n_base + 32 + lr)]);
        prow[r] = v;
    }
#pragma unroll
    for (int r = 0; r < 16; ++r) {
        float v = prow[r];
        v += __shfl_xor(v, 1);
        v += __shfl_xor(v, 2);
        v += __shfl_xor(v, 4);
        v += __shfl_xor(v, 8);
        v += __shfl_xor(v, 16);
        if (lr == 0) {
            int row = (r & 3) + 8 * (r >> 2) + 4 * hf;
            Kacc[wid][row] = v;
        }
    }
    __syncthreads();

    if (t < 32) {
        float K = Kacc[0][t] + Kacc[1][t] + Kacc[2][t] + Kacc[3][t]
                + Kacc[4][t] + Kacc[5][t] + Kacc[6][t] + Kacc[7][t];
        int ti = t >> 3, tj = t & 7;
        int i = i0 + ti, j = j0 + tj;
        float a0 = Ainp[0];
        out[i * 256 + j] = a0 * a0 * K * kinv[i] * kinv[256 + j];
    }
}

// ---------------- launcher ----------------
extern "C" void kernel_launch(void* const* d_in, const int* in_sizes, int n_in,
                              void* d_out, int out_size, void* d_ws, size_t ws_size,
                              hipStream_t stream) {
    const int*   X1 = (const int*)d_in[0];
    const int*   X2 = (const int*)d_in[1];
    const float* W  = (const float*)d_in[2];
    const float* b  = (const float*)d_in[3];
    const float* wp = (const float*)d_in[4];
    const float* a  = (const float*)d_in[5];
    float* out = (float*)d_out;

    char* ws = (char*)d_ws;
    unsigned short* Tb    = (unsigned short*)(ws + 0);         //    458,752
    float*          Tdiag = (float*)(ws + 458752);             //     49,152
    float*          w32   = (float*)(ws + 507904);             //  1,048,576
    unsigned short* wswz  = (unsigned short*)(ws + 1556480);   //    524,288
    float*          kinv  = (float*)(ws + 2080768);            //      2,048
    uint8_t*        X8    = (uint8_t*)(ws + 2082816);          //    262,144
    unsigned short* Abz   = (unsigned short*)(ws + 2344960);   // 11,010,048
    unsigned short* Wbz   = (unsigned short*)(ws + 13355008);  // 57,802,752
    float*          Ep    = (float*)(ws + 71157760);           // 44,040,192 (end 115,197,952)

    prep_kernel<<<PB_TOTAL, 256, 0, stream>>>(X1, X2, W, wp, X8, w32, wswz, Wbz, Abz);
    e_mfma_v5<<<672, 256, 0, stream>>>(Abz, Wbz, Ep);
    t_kernel<<<512, 256, 0, stream>>>(Ep, b, Tb, Tdiag);
    k_kernel<<<128, 512, 0, stream>>>(X8, Tdiag, w32, kinv);
    k4_kernel<<<dim3(64, 32), 512, 0, stream>>>(X8, Tb, wswz, kinv, a, out);
}

// Round 11
// 310.843 us; speedup vs baseline: 1.4139x; 1.0262x over previous
//
#include <hip/hip_runtime.h>
#include <cstdint>
#include <cstddef>

// ---------------- types / helpers ----------------
typedef __attribute__((ext_vector_type(8))) __bf16 bf16x8;
typedef __attribute__((ext_vector_type(4))) __bf16 bf16x4;
typedef __attribute__((ext_vector_type(4))) float f32x4;
typedef __attribute__((ext_vector_type(16))) float f32x16;

__device__ __forceinline__ unsigned short f2b(float x) {
    uint32_t u = __float_as_uint(x);
    u += 0x7FFFu + ((u >> 16) & 1u);   // RNE
    return (unsigned short)(u >> 16);
}
__device__ __forceinline__ float b2f(unsigned short h) {
    return __uint_as_float(((uint32_t)h) << 16);
}

// async global->LDS, 16B per lane. LDS dest is wave-uniform base (+lane*16 by HW).
__device__ __forceinline__ void gl16(const void* g, void* l) {
    __builtin_amdgcn_global_load_lds((const __attribute__((address_space(1))) uint32_t*)g,
                                     (__attribute__((address_space(3))) uint32_t*)l, 16, 0, 0);
}

#define L_SEQ 512
#define N_AA 21
#define DDIM 128
#define NCOL 2688        // 21*128
#define NSEQ 512         // 256 + 256
#define TBSTRIDE 448     // Tb row stride (u16), 441 used
#define KTOT 10752       // 512*21
#define ZCH 8            // k-chunks (partial-slab count)
#define KBTOT 672        // 10752/16 k-subtiles
#define KBCH 84          // 672/8 k-subtiles per chunk

// block-range sizes inside prep_kernel
#define PB_WBZ   2688    // 672 kb x 4 col-windows (gl16-staged fp32 tile)
#define PB_REPACK 1024
#define PB_WBUILD 1024
#define PB_ABZ   2688    // 16*672/4 fragments
#define PB_TOTAL (PB_WBZ + PB_REPACK + PB_WBUILD + PB_ABZ)

#define SH_PAD 516       // Sh row stride (u16): 258 dw, gcd(258,32)=2 -> 2-way (free) on b64

// ---------------- kernel 1: fused prologue ----------------
// Independent sub-jobs, dispatched by blockIdx range:
//   [0, 2688)      : W fp32 -> Wbz bf16 fragment-swizzled (gl16-staged fp32 tile)
//   [+1024)        : X1/X2 int32 -> X8 u8
//   [+1024)        : w32 = sigmoid(wm), wswz = bf16 MFMA-frag order
//   [+2688)        : one-hot A -> Abz bf16 fragment-swizzled (2 X reads per frag)
__global__ __launch_bounds__(256) void prep_kernel(const int* X1, const int* X2,
                                                   const float* W, const float* wp,
                                                   uint8_t* X8,
                                                   float* w32, unsigned short* wswz,
                                                   unsigned short* Wbz, unsigned short* Abz) {
    __shared__ float Wf[16 * 672];               // 43 KB, only used by the Wbz job
    int bid = blockIdx.x;
    int t = threadIdx.x;
    if (bid < PB_WBZ) {
        int kb = bid >> 2, cw = bid & 3;         // 16 rows starting r0, 672-col window c0
        int r0 = kb * 16, c0 = cw * 672;
        // phase 1: stage 16x672 fp32 tile via gl16. Tile byte g = i*1024 + lane*16;
        // row = g/2688 (rows are 2688 B = 16B-multiple, no straddle), colb = g%2688.
        {
            int wid = t >> 6, lane = t & 63;
            const char* Wbase = (const char*)(W + (size_t)r0 * NCOL + c0);
            for (int i = wid; i < 42; i += 4) {
                int g = i * 1024 + lane * 16;
                int row = g / 2688;
                int colb = g - row * 2688;
                gl16(Wbase + (size_t)row * (NCOL * 4) + colb, (char*)Wf + i * 1024);
            }
        }
        asm volatile("s_waitcnt vmcnt(0)" ::: "memory");
        __syncthreads();
        // phase 2: gather fragment order from fp32 LDS, convert, contiguous uint4 write
        for (int e = t; e < 21 * 64; e += 256) {
            int fi = e >> 6, sl = e & 63;
            int lr = sl & 31, hf = sl >> 5;
            union { uint4 q; unsigned short s[8]; } o;
#pragma unroll
            for (int j = 0; j < 8; ++j) o.s[j] = f2b(Wf[(hf * 8 + j) * 672 + fi * 32 + lr]);
            int cb = cw * 21 + fi;
            *(uint4*)&Wbz[((size_t)cb * KBTOT + kb) * 512 + sl * 8] = o.q;
        }
        return;
    }
    bid -= PB_WBZ;
    if (bid < PB_REPACK) {
        int e = bid * 256 + t;             // 262,144
        if (e < 131072) X8[e] = (uint8_t)X1[e];
        else            X8[e] = (uint8_t)X2[e - 131072];
        return;
    }
    bid -= PB_REPACK;
    if (bid < PB_WBUILD) {
        int e = bid * 256 + t;             // 262,144 = 512*512
        int p = e >> 9, q = e & 511;
        float x = 0.0f;
        if (p > q)      x = wp[p * (p - 1) / 2 + q];
        else if (p < q) x = wp[q * (q - 1) / 2 + p];
        float s = 1.0f / (1.0f + expf(-x));
        w32[e] = s;
        int nb = p >> 5, lr = p & 31;
        int kb = q >> 4, hf = (q >> 3) & 1, j = q & 7;
        wswz[(size_t)((nb * 32 + kb) * 512) + (hf * 32 + lr) * 8 + j] = f2b(s);
        return;
    }
    bid -= PB_WBUILD;
    {
        // Abz fragment (mb,kb): lane (hf,lr) holds onehot(X[mb*32+lr], k=kb*16+hf*8+j)
        // k0..k0+7 spans at most two l values -> 2 X reads instead of 8.
        int f = bid * 4 + (t >> 6);        // 0..10751
        int lane = t & 63, lr = lane & 31, hf = lane >> 5;
        int mb = f / KBTOT, kb = f - mb * KBTOT;
        int m = mb * 32 + lr;
        const int* Xrow = (m < 256) ? (X1 + (size_t)m * L_SEQ) : (X2 + (size_t)(m - 256) * L_SEQ);
        int k0 = kb * 16 + hf * 8;
        int l0 = k0 / N_AA;
        int x0 = Xrow[l0];
        int x1 = (l0 < L_SEQ - 1) ? Xrow[l0 + 1] : -1;
        union { uint4 q; unsigned short s[8]; } o;
#pragma unroll
        for (int j = 0; j < 8; ++j) {
            int k = k0 + j;
            int l = k / N_AA;
            int aa = k - l * N_AA;
            int x = (l == l0) ? x0 : x1;
            o.s[j] = (x == aa) ? (unsigned short)0x3F80u : (unsigned short)0u;
        }
        *(uint4*)&Abz[(size_t)f * 512 + lane * 8] = o.q;
    }
}

// ---------------- kernel 2: Ep[kz] = A @ W (k-chunk partial) — LDS ring, PLAIN STORES ---
__global__ __launch_bounds__(256, 4) void e_mfma_v5(const unsigned short* Abz, const unsigned short* Wbz, float* Ep) {
    __shared__ unsigned short lds[4 * 8 * 512];   // 4 bufs x 8 frags x 1024 B = 32 KB

    int lin = blockIdx.x;
    int s = ((lin & 7) * 84) + (lin >> 3);    // bijective XCD swizzle (672 % 8 == 0)
    int cx = s % 21;
    int rem = s / 21;                          // 0..31
    int my = rem & 3;
    int kz = rem >> 2;                         // 0..7

    int t = threadIdx.x, wid = t >> 6, lane = t & 63;
    int lr = lane & 31, hf = lane >> 5;
    int kb0 = kz * KBCH;

    const unsigned short* Aw = Abz + ((size_t)((my * 4 + wid) * KBTOT + kb0)) * 512 + lane * 8;
    const unsigned short* Bw = Wbz + ((size_t)((cx * 4 + wid) * KBTOT + kb0)) * 512 + lane * 8;
    unsigned short* La = &lds[wid * 512];
    unsigned short* Lb = &lds[(4 + wid) * 512];

#define STG(buf_, kb_) do { \
        gl16(Aw + (size_t)(kb_) * 512, La + (buf_) * 4096); \
        gl16(Bw + (size_t)(kb_) * 512, Lb + (buf_) * 4096); \
    } while (0)

    int alo = (wid & 1) * 2;          // A frag slots this wave consumes
    int blo = 4 + (wid >> 1) * 2;     // B frag slots

    f32x16 acc00, acc01, acc10, acc11;
#pragma unroll
    for (int r = 0; r < 16; ++r) { acc00[r] = 0.f; acc01[r] = 0.f; acc10[r] = 0.f; acc11[r] = 0.f; }

#define COMPUTE(kb_) do { \
        const unsigned short* base = &lds[((kb_) & 3) * 4096]; \
        bf16x8 a0 = *(const bf16x8*)(base + (alo + 0) * 512 + lane * 8); \
        bf16x8 a1 = *(const bf16x8*)(base + (alo + 1) * 512 + lane * 8); \
        bf16x8 b0 = *(const bf16x8*)(base + (blo + 0) * 512 + lane * 8); \
        bf16x8 b1 = *(const bf16x8*)(base + (blo + 1) * 512 + lane * 8); \
        acc00 = __builtin_amdgcn_mfma_f32_32x32x16_bf16(a0, b0, acc00, 0, 0, 0); \
        acc01 = __builtin_amdgcn_mfma_f32_32x32x16_bf16(a0, b1, acc01, 0, 0, 0); \
        acc10 = __builtin_amdgcn_mfma_f32_32x32x16_bf16(a1, b0, acc10, 0, 0, 0); \
        acc11 = __builtin_amdgcn_mfma_f32_32x32x16_bf16(a1, b1, acc11, 0, 0, 0); \
    } while (0)

    // prologue: stage kb=0,1,2 (6 loads/wave outstanding)
    STG(0, 0); STG(1, 1); STG(2, 2);

#pragma unroll 1
    for (int kb = 0; kb < KBCH - 3; ++kb) {
        STG((kb + 3) & 3, kb + 3);                      // overwrite buffer read at kb-1 (fenced below)
        asm volatile("s_waitcnt vmcnt(6)" ::: "memory"); // own kb loads landed; 3 steps stay in flight
        __builtin_amdgcn_s_barrier();                    // all waves' kb loads landed
        __builtin_amdgcn_sched_barrier(0);
        COMPUTE(kb);
        __builtin_amdgcn_sched_barrier(0);
        __builtin_amdgcn_s_barrier();                    // all waves done reading buf[kb&3] before restage
    }
    // tail: kb = KBCH-3 .. KBCH-1 (no more staging)
    asm volatile("s_waitcnt vmcnt(4)" ::: "memory");
    __builtin_amdgcn_s_barrier();
    __builtin_amdgcn_sched_barrier(0);
    COMPUTE(KBCH - 3);
    asm volatile("s_waitcnt vmcnt(2)" ::: "memory");
    __builtin_amdgcn_s_barrier();
    __builtin_amdgcn_sched_barrier(0);
    COMPUTE(KBCH - 2);
    asm volatile("s_waitcnt vmcnt(0)" ::: "memory");
    __builtin_amdgcn_s_barrier();
    __builtin_amdgcn_sched_barrier(0);
    COMPUTE(KBCH - 1);

#undef STG
#undef COMPUTE

    int mb0 = my * 4 + (wid & 1) * 2;        // m-fragment index (32-row units)
    int cb0 = cx * 4 + (wid >> 1) * 2;       // c-fragment index (32-col units)
    float* slab = Ep + (size_t)kz * NSEQ * NCOL;
#pragma unroll
    for (int r = 0; r < 16; ++r) {
        int row = (r & 3) + 8 * (r >> 2) + 4 * hf;
        float* base = slab + (size_t)(mb0 * 32 + row) * NCOL + cb0 * 32 + lr;
        base[0] = acc00[r];
        base[32] = acc01[r];
        base[(size_t)32 * NCOL] = acc10[r];
        base[(size_t)32 * NCOL + 32] = acc11[r];
    }
}

// ---------------- kernel 3: T[n] = E[n] @ E[n]^T, E[n] = sum_z Ep[z][n] + bias --------
__global__ __launch_bounds__(256) void t_kernel(const float* Ep, const float* bvec,
                                                unsigned short* Tb, float* Tdiag) {
    __shared__ float4 Es4[21 * 33];
    int t = threadIdx.x, n = blockIdx.x;
    for (int idx = t; idx < 672; idx += 256) {          // 672 float4 = 2688 cols
        const float4* bp = (const float4*)(bvec + idx * 4);
        float4 acc = *bp;
#pragma unroll
        for (int z = 0; z < ZCH; ++z) {
            float4 v = *(const float4*)(Ep + ((size_t)z * NSEQ + n) * NCOL + idx * 4);
            acc.x += v.x; acc.y += v.y; acc.z += v.z; acc.w += v.w;
        }
        int r = idx >> 5, d = idx & 31;
        Es4[r * 33 + d] = acc;
    }
    __syncthreads();
    for (int e = t; e < 441; e += 256) {
        int r = e / 21, c = e - r * 21;
        const float4* ar = &Es4[r * 33];
        const float4* br = &Es4[c * 33];
        float s = 0.f;
#pragma unroll 8
        for (int d = 0; d < 32; ++d) {
            float4 a = ar[d], b = br[d];
            s += a.x * b.x + a.y * b.y + a.z * b.z + a.w * b.w;
        }
        Tb[(size_t)n * TBSTRIDE + e] = f2b(0.5f * s);
        if (r == c) Tdiag[n * 24 + r] = s;
    }
}

// ---------------- kernel 4: kinv — coalesced wave-per-row bilinear form ----------------
__global__ __launch_bounds__(512) void k_kernel(const uint8_t* X8, const float* Tdiag, const float* w32, float* kinv) {
    __shared__ __align__(16) float dvec[4][512];
    __shared__ float Td[4][21];
    __shared__ float wred[4][8];
    int t = threadIdx.x, n0 = blockIdx.x * 4;
    if (t < 84) Td[t / 21][t % 21] = Tdiag[(size_t)(n0 + t / 21) * 24 + (t % 21)];
    __syncthreads();
    for (int e = t; e < 2048; e += 512) {
        int nn = e >> 9, l = e & 511;
        dvec[nn][l] = Td[nn][X8[(size_t)(n0 + nn) * 512 + l]];
    }
    __syncthreads();
    int wid = t >> 6, lane = t & 63;
    int q0 = lane * 8;

    float4 dA0 = *(const float4*)&dvec[0][q0], dA1 = *(const float4*)&dvec[0][q0 + 4];
    float4 dB0 = *(const float4*)&dvec[1][q0], dB1 = *(const float4*)&dvec[1][q0 + 4];
    float4 dC0 = *(const float4*)&dvec[2][q0], dC1 = *(const float4*)&dvec[2][q0 + 4];
    float4 dD0 = *(const float4*)&dvec[3][q0], dD1 = *(const float4*)&dvec[3][q0 + 4];

    float4 rA0 = {0,0,0,0}, rA1 = {0,0,0,0}, rB0 = {0,0,0,0}, rB1 = {0,0,0,0};
    float4 rC0 = {0,0,0,0}, rC1 = {0,0,0,0}, rD0 = {0,0,0,0}, rD1 = {0,0,0,0};

#define FMA4(R, W, S) do { (R).x += (W).x * (S); (R).y += (W).y * (S); (R).z += (W).z * (S); (R).w += (W).w * (S); } while (0)
    for (int p = wid; p < 512; p += 8) {
        const float4* wr = (const float4*)(w32 + (size_t)p * 512 + q0);
        float4 w0v = wr[0], w1v = wr[1];
        float a = dvec[0][p], b = dvec[1][p], c = dvec[2][p], d = dvec[3][p];
        FMA4(rA0, w0v, a); FMA4(rA1, w1v, a);
        FMA4(rB0, w0v, b); FMA4(rB1, w1v, b);
        FMA4(rC0, w0v, c); FMA4(rC1, w1v, c);
        FMA4(rD0, w0v, d); FMA4(rD1, w1v, d);
    }
#undef FMA4

#define DOT8(R0, R1, D0, D1) ((R0).x*(D0).x + (R0).y*(D0).y + (R0).z*(D0).z + (R0).w*(D0).w + \
                              (R1).x*(D1).x + (R1).y*(D1).y + (R1).z*(D1).z + (R1).w*(D1).w)
    float s0 = DOT8(rA0, rA1, dA0, dA1);
    float s1 = DOT8(rB0, rB1, dB0, dB1);
    float s2 = DOT8(rC0, rC1, dC0, dC1);
    float s3 = DOT8(rD0, rD1, dD0, dD1);
#undef DOT8

#pragma unroll
    for (int off = 1; off < 64; off <<= 1) {
        s0 += __shfl_xor(s0, off);
        s1 += __shfl_xor(s1, off);
        s2 += __shfl_xor(s2, off);
        s3 += __shfl_xor(s3, off);
    }
    if (lane == 0) { wred[0][wid] = s0; wred[1][wid] = s1; wred[2][wid] = s2; wred[3][wid] = s3; }
    __syncthreads();
    if (t < 4) {
        float kk = 0.f;
#pragma unroll
        for (int w = 0; w < 8; ++w) kk += wred[t][w];
        kinv[n0 + t] = 1.0f / sqrtf(kk);
    }
}

// ---------------- kernel 5: main pair GEMM — 8 waves, 4-deep B register ring ----------
// Round-10 diagnosis: kt loop had ~2-deep B lookahead -> each MFMA pair paid L2 latency.
// Static 4-slot register ring (rule #20: all indices compile-time) keeps ~8 B loads in
// flight per wave. LDS unchanged (53 KB, 3 blocks/CU); VGPR 40 -> ~72 (cap 85 at (512,6)).
__global__ __launch_bounds__(512, 6) void k4_kernel(const uint8_t* X8, const unsigned short* Tb,
                                                    const unsigned short* wswz, const float* kinv,
                                                    const float* Ainp, float* out) {
    __shared__ unsigned short Sh[32 * SH_PAD];
    __shared__ unsigned short Ts1h[4 * TBSTRIDE];
    __shared__ unsigned short Ts2h[8 * TBSTRIDE];
    __shared__ unsigned short A21[4 * 512];
    __shared__ uint8_t Xs2[8 * 512];
    __shared__ float Kacc[8][32];

    int t = threadIdx.x;
    int i0 = blockIdx.x * 4;
    int j0 = blockIdx.y * 8;

    for (int e = t; e < 4 * 512; e += 512)
        A21[e] = (unsigned short)(21 * X8[(size_t)(i0 + (e >> 9)) * 512 + (e & 511)]);
    {
        const uint32_t* s2 = (const uint32_t*)(X8 + (size_t)(256 + j0) * 512);
        uint32_t* d2 = (uint32_t*)Xs2;
        for (int e = t; e < 1024; e += 512) d2[e] = s2[e];
    }
    {
        // Tb rows are already 0.5*T in bf16 — straight u32 copies (448 u16 = 224 u32 per row)
        uint32_t* d1 = (uint32_t*)Ts1h;
        for (int e = t; e < 4 * 224; e += 512) {
            int r = e / 224, w = e - r * 224;
            d1[e] = ((const uint32_t*)(Tb + (size_t)(i0 + r) * TBSTRIDE))[w];
        }
        uint32_t* d2 = (uint32_t*)Ts2h;
        for (int e = t; e < 8 * 224; e += 512) {
            int r = e / 224, w = e - r * 224;
            d2[e] = ((const uint32_t*)(Tb + (size_t)(256 + j0 + r) * TBSTRIDE))[w];
        }
    }
    __syncthreads();

    // build S tile: 4 elems per thread-iter, packed u64 write (8B-aligned at SH_PAD=516)
    for (int e4 = t; e4 < 32 * 128; e4 += 512) {
        int pr = e4 >> 7, p = (e4 & 127) * 4;
        int ti = pr >> 3, tj = pr & 7;
        uint64_t a4 = *(const uint64_t*)&A21[ti * 512 + p];   // 4 u16 (a*21)
        uint32_t b4 = *(const uint32_t*)&Xs2[tj * 512 + p];   // 4 u8
        const unsigned short* T1 = &Ts1h[ti * TBSTRIDE];
        const unsigned short* T2 = &Ts2h[tj * TBSTRIDE];
        uint64_t outw = 0;
#pragma unroll
        for (int u = 0; u < 4; ++u) {
            int idx = (int)((a4 >> (16 * u)) & 0xFFFFu) + (int)((b4 >> (8 * u)) & 0xFFu);
            float v = b2f(T1[idx]) + b2f(T2[idx]);
            outw |= (uint64_t)f2b(v) << (16 * u);
        }
        *(uint64_t*)&Sh[pr * SH_PAD + p] = outw;
    }
    __syncthreads();

    int wid = t >> 6, lane = t & 63;
    int lr = lane & 31, hf = lane >> 5;
    int n_base = wid * 64;

    const unsigned short* Sa = &Sh[lr * SH_PAD + hf * 8];
    const unsigned short* Bz0 = wswz + (size_t)((wid * 2 + 0) * 32) * 512 + lane * 8;
    const unsigned short* Bz1 = wswz + (size_t)((wid * 2 + 1) * 32) * 512 + lane * 8;

    f32x16 acc0, acc1;
#pragma unroll
    for (int j = 0; j < 16; ++j) { acc0[j] = 0.f; acc1[j] = 0.f; }

    bf16x8 rb0_0, rb1_0, rb0_1, rb1_1, rb0_2, rb1_2, rb0_3, rb1_3;

#define LOADB(S, kt_) do { \
        rb0_##S = *(const bf16x8*)(Bz0 + (kt_) * 512); \
        rb1_##S = *(const bf16x8*)(Bz1 + (kt_) * 512); \
    } while (0)

#define STEPK(S, kt_) do { \
        union { bf16x8 v; bf16x4 h[2]; } av; \
        av.h[0] = *(const bf16x4*)(Sa + (kt_) * 16); \
        av.h[1] = *(const bf16x4*)(Sa + (kt_) * 16 + 4); \
        acc0 = __builtin_amdgcn_mfma_f32_32x32x16_bf16(av.v, rb0_##S, acc0, 0, 0, 0); \
        acc1 = __builtin_amdgcn_mfma_f32_32x32x16_bf16(av.v, rb1_##S, acc1, 0, 0, 0); \
    } while (0)

    // prologue: fill ring with kt=0..3 (8 loads in flight)
    LOADB(0, 0); LOADB(1, 1); LOADB(2, 2); LOADB(3, 3);

#pragma unroll 1
    for (int kt = 0; kt < 28; kt += 4) {
        STEPK(0, kt + 0); LOADB(0, kt + 4);
        STEPK(1, kt + 1); LOADB(1, kt + 5);
        STEPK(2, kt + 2); LOADB(2, kt + 6);
        STEPK(3, kt + 3); LOADB(3, kt + 7);
    }
    STEPK(0, 28); STEPK(1, 29); STEPK(2, 30); STEPK(3, 31);

#undef LOADB
#undef STEPK

    float prow[16];
#pragma unroll
    for (int r = 0; r < 16; ++r) {
        int row = (r & 3) + 8 * (r >> 2) + 4 * hf;
        float v = acc0[r] * b2f(Sh[row * SH_PAD + (n_base + lr)]);
        v      += acc1[r] * b2f(Sh[row * SH_PAD + (n_base + 32 + lr)]);
        prow[r] = v;
    }
#pragma unroll
    for (int r = 0; r < 16; ++r) {
        float v = prow[r];
        v += __shfl_xor(v, 1);
        v += __shfl_xor(v, 2);
        v += __shfl_xor(v, 4);
        v += __shfl_xor(v, 8);
        v += __shfl_xor(v, 16);
        if (lr == 0) {
            int row = (r & 3) + 8 * (r >> 2) + 4 * hf;
            Kacc[wid][row] = v;
        }
    }
    __syncthreads();

    if (t < 32) {
        float K = Kacc[0][t] + Kacc[1][t] + Kacc[2][t] + Kacc[3][t]
                + Kacc[4][t] + Kacc[5][t] + Kacc[6][t] + Kacc[7][t];
        int ti = t >> 3, tj = t & 7;
        int i = i0 + ti, j = j0 + tj;
        float a0 = Ainp[0];
        out[i * 256 + j] = a0 * a0 * K * kinv[i] * kinv[256 + j];
    }
}

// ---------------- launcher ----------------
extern "C" void kernel_launch(void* const* d_in, const int* in_sizes, int n_in,
                              void* d_out, int out_size, void* d_ws, size_t ws_size,
                              hipStream_t stream) {
    const int*   X1 = (const int*)d_in[0];
    const int*   X2 = (const int*)d_in[1];
    const float* W  = (const float*)d_in[2];
    const float* b  = (const float*)d_in[3];
    const float* wp = (const float*)d_in[4];
    const float* a  = (const float*)d_in[5];
    float* out = (float*)d_out;

    char* ws = (char*)d_ws;
    unsigned short* Tb    = (unsigned short*)(ws + 0);         //    458,752
    float*          Tdiag = (float*)(ws + 458752);             //     49,152
    float*          w32   = (float*)(ws + 507904);             //  1,048,576
    unsigned short* wswz  = (unsigned short*)(ws + 1556480);   //    524,288
    float*          kinv  = (float*)(ws + 2080768);            //      2,048
    uint8_t*        X8    = (uint8_t*)(ws + 2082816);          //    262,144
    unsigned short* Abz   = (unsigned short*)(ws + 2344960);   // 11,010,048
    unsigned short* Wbz   = (unsigned short*)(ws + 13355008);  // 57,802,752
    float*          Ep    = (float*)(ws + 71157760);           // 44,040,192 (end 115,197,952)

    prep_kernel<<<PB_TOTAL, 256, 0, stream>>>(X1, X2, W, wp, X8, w32, wswz, Wbz, Abz);
    e_mfma_v5<<<672, 256, 0, stream>>>(Abz, Wbz, Ep);
    t_kernel<<<512, 256, 0, stream>>>(Ep, b, Tb, Tdiag);
    k_kernel<<<128, 512, 0, stream>>>(X8, Tdiag, w32, kinv);
    k4_kernel<<<dim3(64, 32), 512, 0, stream>>>(X8, Tb, wswz, kinv, a, out);
}